// Round 6
// baseline (1083.841 us; speedup 1.0000x reference)
//
#include <hip/hip_runtime.h>
#include <hip/hip_bf16.h>

// SelectiveSSM: B=1, L=2048, D_MODEL=512, D_INNER=1024, D_STATE=16, D_CONV=4
// ESTABLISHED (R0-R5 evidence):
//   - inputs are FP32 (R3 bf16-read NaN'd via mantissa-word NaNs; R4 fp32-read finite)
//   - d_out is FP32 (R5: an unconditional bf16 write of 4096.0 to out[0] was
//     invisible in the fp32-word comparison -> it landed in mantissa bits;
//     reference output dtype is jnp.float32, per the stub's dtype rule)
//   - harness "(bf16, ref=np)" label is tolerance-mode text, not buffer dtype.
// R6: R4 pipeline unchanged, final store fp32. Scratch-adaptive:
//   fp32 scratch 17.05 MB; bf16-scratch fallback 8.66 MB (ws_size still unknown).
// Pipeline: GEMM1a(x-half)->buf0; conv+silu->buf1(xs); xproj->xp;
//           GEMM1b(z-half)->buf0 (x-pre dead); scan: ys in-place into buf1;
//           GEMM2(buf1 @ W_out)->out(fp32).

#define L_SEQ 2048
#define DM 512
#define DI 1024
#define DS 16
#define NXP 33
#define EPS 1e-10f

typedef __hip_bfloat16 bf16;

__device__ __forceinline__ float ldf(const float* p) { return *p; }
__device__ __forceinline__ float ldf(const bf16* p) { return __bfloat162float(*p); }

struct alignas(8) bf16x4 { bf16 x, y, z, w; };

__device__ __forceinline__ float4 ld4(const float* p) { return *(const float4*)p; }
__device__ __forceinline__ float4 ld4(const bf16* p) {
  bf16x4 v = *(const bf16x4*)p;
  return make_float4(__bfloat162float(v.x), __bfloat162float(v.y),
                     __bfloat162float(v.z), __bfloat162float(v.w));
}
__device__ __forceinline__ void st4(float* p, float4 v) { *(float4*)p = v; }
__device__ __forceinline__ void st4(bf16* p, float4 v) {
  bf16x4 o;
  o.x = __float2bfloat16(v.x); o.y = __float2bfloat16(v.y);
  o.z = __float2bfloat16(v.z); o.w = __float2bfloat16(v.w);
  *(bf16x4*)p = o;
}
__device__ __forceinline__ void st1(float* p, float v) { *p = v; }
__device__ __forceinline__ void st1(bf16* p, float v) { *p = __float2bfloat16(v); }

// C[M,N] = A[M,K] @ B[K,N] with explicit leading dims. M,N mult of 64, K mult of 16.
template <typename TA, typename TB, typename TC>
__global__ __launch_bounds__(256)
void gemm_tiled(const TA* __restrict__ A, const TB* __restrict__ B,
                TC* __restrict__ C, int M, int N, int K,
                int lda, int ldb, int ldc) {
  __shared__ __align__(16) float As[16][68];
  __shared__ __align__(16) float Bs[16][68];
  const int tid = threadIdx.x;
  const int tx = tid & 15, ty = tid >> 4;
  const int row0 = blockIdx.y * 64, col0 = blockIdx.x * 64;
  float acc[4][4] = {};
  for (int k0 = 0; k0 < K; k0 += 16) {
#pragma unroll
    for (int j = 0; j < 4; ++j) {
      int i = tid + j * 256;
      int m = i >> 4, kk = i & 15;
      As[kk][m] = ldf(A + (size_t)(row0 + m) * lda + (k0 + kk));
    }
#pragma unroll
    for (int j = 0; j < 4; ++j) {
      int i = tid + j * 256;
      int n = i & 63, kk = i >> 6;
      Bs[kk][n] = ldf(B + (size_t)(k0 + kk) * ldb + (col0 + n));
    }
    __syncthreads();
#pragma unroll
    for (int kk = 0; kk < 16; ++kk) {
      float4 a4 = *(const float4*)&As[kk][ty * 4];
      float4 b4 = *(const float4*)&Bs[kk][tx * 4];
      float av[4] = {a4.x, a4.y, a4.z, a4.w};
      float bv[4] = {b4.x, b4.y, b4.z, b4.w};
#pragma unroll
      for (int i = 0; i < 4; ++i)
#pragma unroll
        for (int j = 0; j < 4; ++j)
          acc[i][j] = fmaf(av[i], bv[j], acc[i][j]);
    }
    __syncthreads();
  }
#pragma unroll
  for (int i = 0; i < 4; ++i) {
    float4 v = make_float4(acc[i][0], acc[i][1], acc[i][2], acc[i][3]);
    st4(C + (size_t)(row0 + ty * 4 + i) * ldc + (col0 + tx * 4), v);
  }
}

// Depthwise causal conv (width 4) + bias + SiLU: buf0(x-pre) -> buf1(xs).
template <typename T>
__global__ __launch_bounds__(256)
void conv_silu_kernel(const T* __restrict__ xpre, const float* __restrict__ conv_w,
                      const float* __restrict__ conv_b, T* __restrict__ xs) {
  int idx = blockIdx.x * 256 + threadIdx.x;  // l*1024 + d
  int d = idx & (DI - 1);
  int l = idx >> 10;
  float acc = conv_b[d];
#pragma unroll
  for (int k = 0; k < 4; ++k) {
    int ls = l + k - 3;
    if (ls >= 0) acc = fmaf(ldf(xpre + (size_t)ls * DI + d), conv_w[d * 4 + k], acc);
  }
  st1(xs + idx, acc / (1.f + __expf(-acc)));
}

// xp[l, 0:33] = xs[l, :] @ W_xproj
template <typename T>
__global__ __launch_bounds__(64)
void xproj_kernel(const T* __restrict__ xs, const float* __restrict__ W_xproj,
                  float* __restrict__ xp) {
  __shared__ float row[DI];
  int l = blockIdx.x;
  for (int i = threadIdx.x; i < DI; i += 64) row[i] = ldf(xs + (size_t)l * DI + i);
  __syncthreads();
  int j = threadIdx.x;
  if (j < NXP) {
    float acc = 0.f;
#pragma unroll 8
    for (int i = 0; i < DI; ++i)
      acc = fmaf(row[i], W_xproj[i * NXP + j], acc);
    xp[l * NXP + j] = acc;
  }
}

// Sequential scan over L. One wave per block; 4 d-channels x 16 states.
// Faithful to the reference's clamped log-cumsum formulation:
//   cs += log(max(exp(delta*A), EPS));  S += delta*Bp*xs / max(A_shift, EPS);
//   h   = exp(cs) * S / max(A_bar, EPS);  y = sum_s Cp*h + D*xs, gated silu(z).
// Writes gated output IN PLACE into buf1 (xs) — per-block private columns.
#define LCHUNK 128
template <typename T>
__global__ __launch_bounds__(64)
void scan_kernel(T* __restrict__ xsbuf, const T* __restrict__ zbuf,
                 const float* __restrict__ xp,
                 const float* __restrict__ dt_w, const float* __restrict__ dt_b,
                 const float* __restrict__ A_log, const float* __restrict__ Dvec) {
  __shared__ __align__(16) float sxp[LCHUNK * NXP];
  __shared__ __align__(16) float sxs[LCHUNK * 4];
  __shared__ __align__(16) float sz[LCHUNK * 4];
  __shared__ __align__(16) float sdt[LCHUNK * 4];
  __shared__ __align__(16) float sys[LCHUNK * 4];
  const int lane = threadIdx.x;
  const int s = lane & 15, dl = lane >> 4;
  const int d0 = blockIdx.x * 4;
  const float As = -expf(A_log[s]);
  const float Dd = Dvec[d0 + dl];
  float dtw[4], dtb[4];
#pragma unroll
  for (int c = 0; c < 4; ++c) {
    dtw[c] = dt_w[d0 + c];
    dtb[c] = dt_b[d0 + c];
  }
  float cs = 0.f, S = 0.f, acum_prev = 1.f;
  for (int l0 = 0; l0 < L_SEQ; l0 += LCHUNK) {
    for (int i = lane; i < LCHUNK * NXP; i += 64) sxp[i] = xp[l0 * NXP + i];
    for (int i = lane; i < LCHUNK; i += 64) {
      *(float4*)&sxs[i * 4] = ld4(xsbuf + (size_t)(l0 + i) * DI + d0);
      *(float4*)&sz[i * 4] = ld4(zbuf + (size_t)(l0 + i) * DI + d0);
      float x0 = xp[(l0 + i) * NXP];
#pragma unroll
      for (int c = 0; c < 4; ++c)
        sdt[i * 4 + c] = log1pf(expf(fmaf(x0, dtw[c], dtb[c])));
    }
    __syncthreads();
    for (int i = 0; i < LCHUNK; ++i) {
      float bp = sxp[i * NXP + 1 + s];
      float cp = sxp[i * NXP + 17 + s];
      float xv = sxs[i * 4 + dl];
      float dt = sdt[i * 4 + dl];
      float abar = expf(dt * As);
      float lab = logf(fmaxf(abar, EPS));
      cs += lab;
      float acum = expf(cs);
      float wbx = (dt * bp * xv) / fmaxf(acum_prev, EPS);
      S += wbx;
      float h = (acum * S) / fmaxf(abar, EPS);
      float contrib = cp * h;
      acum_prev = acum;
      contrib += __shfl_xor(contrib, 8);
      contrib += __shfl_xor(contrib, 4);
      contrib += __shfl_xor(contrib, 2);
      contrib += __shfl_xor(contrib, 1);
      if (s == 0) {
        float zv = sz[i * 4 + dl];
        float yv = contrib + Dd * xv;
        sys[i * 4 + dl] = yv * zv / (1.f + __expf(-zv));
      }
    }
    __syncthreads();
    for (int i = lane; i < LCHUNK; i += 64)
      st4(xsbuf + (size_t)(l0 + i) * DI + d0, *(const float4*)&sys[i * 4]);
    __syncthreads();
  }
}

template <typename T>
static void run_pipeline(const float* x, const float* W_in, const float* conv_w,
                         const float* conv_b, const float* W_xproj, const float* dt_w,
                         const float* dt_b, const float* A_log, const float* Dvec,
                         const float* W_out, float* out, void* ws, hipStream_t stream) {
  const size_t nbuf = (size_t)L_SEQ * DI;
  T* buf0 = (T*)ws;
  T* buf1 = buf0 + nbuf;
  float* xp = (float*)(buf1 + nbuf);

  // 1a) buf0 = x @ W_in[:, 0:1024]   (x-half)
  gemm_tiled<float, float, T><<<dim3(DI / 64, L_SEQ / 64), 256, 0, stream>>>(
      x, W_in, buf0, L_SEQ, DI, DM, DM, 2 * DI, DI);
  // 2) conv + silu -> buf1 (xs)
  conv_silu_kernel<T><<<L_SEQ * DI / 256, 256, 0, stream>>>(buf0, conv_w, conv_b, buf1);
  // 3) xp = xs @ W_xproj
  xproj_kernel<T><<<L_SEQ, 64, 0, stream>>>(buf1, W_xproj, xp);
  // 1b) buf0 = x @ W_in[:, 1024:2048]  (z-half; x-pre is dead now)
  gemm_tiled<float, float, T><<<dim3(DI / 64, L_SEQ / 64), 256, 0, stream>>>(
      x, W_in + DI, buf0, L_SEQ, DI, DM, DM, 2 * DI, DI);
  // 4) scan + gate: ys written in place into buf1
  scan_kernel<T><<<DI / 4, 64, 0, stream>>>(buf1, buf0, xp, dt_w, dt_b, A_log, Dvec);
  // 5) out = ys @ W_out  (2048 x 512 x 1024), FP32 store
  gemm_tiled<T, float, float><<<dim3(DM / 64, L_SEQ / 64), 256, 0, stream>>>(
      buf1, W_out, out, L_SEQ, DM, DI, DI, DM, DM);
}

extern "C" void kernel_launch(void* const* d_in, const int* in_sizes, int n_in,
                              void* d_out, int out_size, void* d_ws, size_t ws_size,
                              hipStream_t stream) {
  const float* x       = (const float*)d_in[0];
  const float* W_in    = (const float*)d_in[1];
  const float* conv_w  = (const float*)d_in[2];
  const float* conv_b  = (const float*)d_in[3];
  const float* W_xproj = (const float*)d_in[4];
  const float* dt_w    = (const float*)d_in[5];
  const float* dt_b    = (const float*)d_in[6];
  const float* A_log   = (const float*)d_in[7];
  const float* Dvec    = (const float*)d_in[8];
  const float* W_out   = (const float*)d_in[9];
  float* out = (float*)d_out;

  const size_t nbuf = (size_t)L_SEQ * DI;
  const size_t need_f32  = 2 * nbuf * sizeof(float) + (size_t)L_SEQ * NXP * sizeof(float);
  const size_t need_bf16 = 2 * nbuf * sizeof(bf16)  + (size_t)L_SEQ * NXP * sizeof(float);

  if (ws_size >= need_f32) {
    run_pipeline<float>(x, W_in, conv_w, conv_b, W_xproj, dt_w, dt_b, A_log, Dvec,
                        W_out, out, d_ws, stream);
  } else if (ws_size >= need_bf16) {
    run_pipeline<bf16>(x, W_in, conv_w, conv_b, W_xproj, dt_w, dt_b, A_log, Dvec,
                       W_out, out, d_ws, stream);
  }
  // If neither fits, out stays zero -> absmax 2.17 tells us ws_size < 8.66 MB.
}

// Round 7
// 820.418 us; speedup vs baseline: 1.3211x; 1.3211x over previous
//
#include <hip/hip_runtime.h>
#include <hip/hip_bf16.h>

// SelectiveSSM: B=1, L=2048, D_MODEL=512, D_INNER=1024, D_STATE=16, D_CONV=4
// ESTABLISHED: inputs fp32, d_out fp32 (R6 passed, absmax 3.9e-3, 1084 us).
// R7: scan fast-math rewrite. R6 scan = 837 us (77%), latency-bound at 3%
// occupancy with precise expf/logf/div software sequences in the serial chain.
// Change: log2-domain scan state + HW v_exp_f32/v_rcp_f32:
//   log(max(exp(u),EPS)) == max(u, lnEPS) exactly -> no expf/logf pair;
//   cs2 tracked in log2 units (As2 pre-scaled by log2e); divides -> v_rcp.
// Semantics preserved: cs += log(max(exp(dt*A),EPS)); S += dt*B*x/max(acum_prev,EPS);
//                      h = exp(cs)*S/max(exp(dt*A),EPS).

#define L_SEQ 2048
#define DM 512
#define DI 1024
#define DS 16
#define NXP 33
#define EPS 1e-10f
#define LOG2E 1.44269504088896340736f
#define LOG2EPS -33.219280948873623478f  // log2(1e-10)

typedef __hip_bfloat16 bf16;

__device__ __forceinline__ float ldf(const float* p) { return *p; }
__device__ __forceinline__ float ldf(const bf16* p) { return __bfloat162float(*p); }

struct alignas(8) bf16x4 { bf16 x, y, z, w; };

__device__ __forceinline__ float4 ld4(const float* p) { return *(const float4*)p; }
__device__ __forceinline__ float4 ld4(const bf16* p) {
  bf16x4 v = *(const bf16x4*)p;
  return make_float4(__bfloat162float(v.x), __bfloat162float(v.y),
                     __bfloat162float(v.z), __bfloat162float(v.w));
}
__device__ __forceinline__ void st4(float* p, float4 v) { *(float4*)p = v; }
__device__ __forceinline__ void st4(bf16* p, float4 v) {
  bf16x4 o;
  o.x = __float2bfloat16(v.x); o.y = __float2bfloat16(v.y);
  o.z = __float2bfloat16(v.z); o.w = __float2bfloat16(v.w);
  *(bf16x4*)p = o;
}
__device__ __forceinline__ void st1(float* p, float v) { *p = v; }
__device__ __forceinline__ void st1(bf16* p, float v) { *p = __float2bfloat16(v); }

__device__ __forceinline__ float fexp2(float x) { return __builtin_amdgcn_exp2f(x); }
__device__ __forceinline__ float frcp(float x) { return __builtin_amdgcn_rcpf(x); }

// C[M,N] = A[M,K] @ B[K,N] with explicit leading dims. M,N mult of 64, K mult of 16.
template <typename TA, typename TB, typename TC>
__global__ __launch_bounds__(256)
void gemm_tiled(const TA* __restrict__ A, const TB* __restrict__ B,
                TC* __restrict__ C, int M, int N, int K,
                int lda, int ldb, int ldc) {
  __shared__ __align__(16) float As[16][68];
  __shared__ __align__(16) float Bs[16][68];
  const int tid = threadIdx.x;
  const int tx = tid & 15, ty = tid >> 4;
  const int row0 = blockIdx.y * 64, col0 = blockIdx.x * 64;
  float acc[4][4] = {};
  for (int k0 = 0; k0 < K; k0 += 16) {
#pragma unroll
    for (int j = 0; j < 4; ++j) {
      int i = tid + j * 256;
      int m = i >> 4, kk = i & 15;
      As[kk][m] = ldf(A + (size_t)(row0 + m) * lda + (k0 + kk));
    }
#pragma unroll
    for (int j = 0; j < 4; ++j) {
      int i = tid + j * 256;
      int n = i & 63, kk = i >> 6;
      Bs[kk][n] = ldf(B + (size_t)(k0 + kk) * ldb + (col0 + n));
    }
    __syncthreads();
#pragma unroll
    for (int kk = 0; kk < 16; ++kk) {
      float4 a4 = *(const float4*)&As[kk][ty * 4];
      float4 b4 = *(const float4*)&Bs[kk][tx * 4];
      float av[4] = {a4.x, a4.y, a4.z, a4.w};
      float bv[4] = {b4.x, b4.y, b4.z, b4.w};
#pragma unroll
      for (int i = 0; i < 4; ++i)
#pragma unroll
        for (int j = 0; j < 4; ++j)
          acc[i][j] = fmaf(av[i], bv[j], acc[i][j]);
    }
    __syncthreads();
  }
#pragma unroll
  for (int i = 0; i < 4; ++i) {
    float4 v = make_float4(acc[i][0], acc[i][1], acc[i][2], acc[i][3]);
    st4(C + (size_t)(row0 + ty * 4 + i) * ldc + (col0 + tx * 4), v);
  }
}

// Depthwise causal conv (width 4) + bias + SiLU: buf0(x-pre) -> buf1(xs).
template <typename T>
__global__ __launch_bounds__(256)
void conv_silu_kernel(const T* __restrict__ xpre, const float* __restrict__ conv_w,
                      const float* __restrict__ conv_b, T* __restrict__ xs) {
  int idx = blockIdx.x * 256 + threadIdx.x;  // l*1024 + d
  int d = idx & (DI - 1);
  int l = idx >> 10;
  float acc = conv_b[d];
#pragma unroll
  for (int k = 0; k < 4; ++k) {
    int ls = l + k - 3;
    if (ls >= 0) acc = fmaf(ldf(xpre + (size_t)ls * DI + d), conv_w[d * 4 + k], acc);
  }
  st1(xs + idx, acc / (1.f + __expf(-acc)));
}

// xp[l, 0:33] = xs[l, :] @ W_xproj
template <typename T>
__global__ __launch_bounds__(64)
void xproj_kernel(const T* __restrict__ xs, const float* __restrict__ W_xproj,
                  float* __restrict__ xp) {
  __shared__ float row[DI];
  int l = blockIdx.x;
  for (int i = threadIdx.x; i < DI; i += 64) row[i] = ldf(xs + (size_t)l * DI + i);
  __syncthreads();
  int j = threadIdx.x;
  if (j < NXP) {
    float acc = 0.f;
#pragma unroll 8
    for (int i = 0; i < DI; ++i)
      acc = fmaf(row[i], W_xproj[i * NXP + j], acc);
    xp[l * NXP + j] = acc;
  }
}

// Sequential scan over L. One wave per block; 4 d-channels x 16 states.
// log2-domain formulation (exactly equivalent to the reference's clamped
// log-cumsum in real arithmetic):
//   u2 = dt*A*log2e; cs2 += max(u2, log2(EPS)); acum = 2^cs2;
//   S += dt*Bp*xs / max(acum_prev, EPS);  h = acum*S / max(2^u2, EPS).
#define LCHUNK 128
template <typename T>
__global__ __launch_bounds__(64)
void scan_kernel(T* __restrict__ xsbuf, const T* __restrict__ zbuf,
                 const float* __restrict__ xp,
                 const float* __restrict__ dt_w, const float* __restrict__ dt_b,
                 const float* __restrict__ A_log, const float* __restrict__ Dvec) {
  __shared__ __align__(16) float sxp[LCHUNK * NXP];
  __shared__ __align__(16) float sxs[LCHUNK * 4];
  __shared__ __align__(16) float sz[LCHUNK * 4];
  __shared__ __align__(16) float sdt[LCHUNK * 4];
  __shared__ __align__(16) float sys[LCHUNK * 4];
  const int lane = threadIdx.x;
  const int s = lane & 15, dl = lane >> 4;
  const int d0 = blockIdx.x * 4;
  const float As2 = -expf(A_log[s]) * LOG2E;  // pre-scaled: u2 = dt*As2
  const float Dd = Dvec[d0 + dl];
  float dtw[4], dtb[4];
#pragma unroll
  for (int c = 0; c < 4; ++c) {
    dtw[c] = dt_w[d0 + c];
    dtb[c] = dt_b[d0 + c];
  }
  float cs2 = 0.f, S = 0.f, rcp_prev = 1.f;  // 1/max(A_shift,EPS), A_shift[0]=1
  for (int l0 = 0; l0 < L_SEQ; l0 += LCHUNK) {
    for (int i = lane; i < LCHUNK * NXP; i += 64) sxp[i] = xp[l0 * NXP + i];
    for (int i = lane; i < LCHUNK; i += 64) {
      *(float4*)&sxs[i * 4] = ld4(xsbuf + (size_t)(l0 + i) * DI + d0);
      *(float4*)&sz[i * 4] = ld4(zbuf + (size_t)(l0 + i) * DI + d0);
      float x0 = xp[(l0 + i) * NXP];
#pragma unroll
      for (int c = 0; c < 4; ++c)
        sdt[i * 4 + c] = log1pf(expf(fmaf(x0, dtw[c], dtb[c])));
    }
    __syncthreads();
    for (int i = 0; i < LCHUNK; ++i) {
      float bp = sxp[i * NXP + 1 + s];
      float cp = sxp[i * NXP + 17 + s];
      float xv = sxs[i * 4 + dl];
      float dt = sdt[i * 4 + dl];
      float u2 = dt * As2;
      cs2 += fmaxf(u2, LOG2EPS);
      float acum = fexp2(cs2);
      S += (dt * bp * xv) * rcp_prev;          // uses previous step's acum
      rcp_prev = frcp(fmaxf(acum, EPS));
      float h = acum * S * frcp(fmaxf(fexp2(u2), EPS));
      float contrib = cp * h;
      contrib += __shfl_xor(contrib, 8);
      contrib += __shfl_xor(contrib, 4);
      contrib += __shfl_xor(contrib, 2);
      contrib += __shfl_xor(contrib, 1);
      if (s == 0) {
        float zv = sz[i * 4 + dl];
        float yv = contrib + Dd * xv;
        sys[i * 4 + dl] = yv * zv / (1.f + __expf(-zv));
      }
    }
    __syncthreads();
    for (int i = lane; i < LCHUNK; i += 64)
      st4(xsbuf + (size_t)(l0 + i) * DI + d0, *(const float4*)&sys[i * 4]);
    __syncthreads();
  }
}

template <typename T>
static void run_pipeline(const float* x, const float* W_in, const float* conv_w,
                         const float* conv_b, const float* W_xproj, const float* dt_w,
                         const float* dt_b, const float* A_log, const float* Dvec,
                         const float* W_out, float* out, void* ws, hipStream_t stream) {
  const size_t nbuf = (size_t)L_SEQ * DI;
  T* buf0 = (T*)ws;
  T* buf1 = buf0 + nbuf;
  float* xp = (float*)(buf1 + nbuf);

  // 1a) buf0 = x @ W_in[:, 0:1024]   (x-half)
  gemm_tiled<float, float, T><<<dim3(DI / 64, L_SEQ / 64), 256, 0, stream>>>(
      x, W_in, buf0, L_SEQ, DI, DM, DM, 2 * DI, DI);
  // 2) conv + silu -> buf1 (xs)
  conv_silu_kernel<T><<<L_SEQ * DI / 256, 256, 0, stream>>>(buf0, conv_w, conv_b, buf1);
  // 3) xp = xs @ W_xproj
  xproj_kernel<T><<<L_SEQ, 64, 0, stream>>>(buf1, W_xproj, xp);
  // 1b) buf0 = x @ W_in[:, 1024:2048]  (z-half; x-pre is dead now)
  gemm_tiled<float, float, T><<<dim3(DI / 64, L_SEQ / 64), 256, 0, stream>>>(
      x, W_in + DI, buf0, L_SEQ, DI, DM, DM, 2 * DI, DI);
  // 4) scan + gate: ys written in place into buf1
  scan_kernel<T><<<DI / 4, 64, 0, stream>>>(buf1, buf0, xp, dt_w, dt_b, A_log, Dvec);
  // 5) out = ys @ W_out  (2048 x 512 x 1024), FP32 store
  gemm_tiled<T, float, float><<<dim3(DM / 64, L_SEQ / 64), 256, 0, stream>>>(
      buf1, W_out, out, L_SEQ, DM, DI, DI, DM, DM);
}

extern "C" void kernel_launch(void* const* d_in, const int* in_sizes, int n_in,
                              void* d_out, int out_size, void* d_ws, size_t ws_size,
                              hipStream_t stream) {
  const float* x       = (const float*)d_in[0];
  const float* W_in    = (const float*)d_in[1];
  const float* conv_w  = (const float*)d_in[2];
  const float* conv_b  = (const float*)d_in[3];
  const float* W_xproj = (const float*)d_in[4];
  const float* dt_w    = (const float*)d_in[5];
  const float* dt_b    = (const float*)d_in[6];
  const float* A_log   = (const float*)d_in[7];
  const float* Dvec    = (const float*)d_in[8];
  const float* W_out   = (const float*)d_in[9];
  float* out = (float*)d_out;

  const size_t nbuf = (size_t)L_SEQ * DI;
  const size_t need_f32  = 2 * nbuf * sizeof(float) + (size_t)L_SEQ * NXP * sizeof(float);
  const size_t need_bf16 = 2 * nbuf * sizeof(bf16)  + (size_t)L_SEQ * NXP * sizeof(float);

  if (ws_size >= need_f32) {
    run_pipeline<float>(x, W_in, conv_w, conv_b, W_xproj, dt_w, dt_b, A_log, Dvec,
                        W_out, out, d_ws, stream);
  } else if (ws_size >= need_bf16) {
    run_pipeline<bf16>(x, W_in, conv_w, conv_b, W_xproj, dt_w, dt_b, A_log, Dvec,
                       W_out, out, d_ws, stream);
  }
}

// Round 8
// 523.130 us; speedup vs baseline: 2.0718x; 1.5683x over previous
//
#include <hip/hip_runtime.h>
#include <hip/hip_bf16.h>

// SelectiveSSM: B=1, L=2048, D_MODEL=512, D_INNER=1024, D_STATE=16, D_CONV=4
// ESTABLISHED: inputs fp32, d_out fp32. R7: 820 us, scan 570 us (70%),
// VALUBusy 7.7% -> latency-bound: per-step scalar ds_reads (~120cyc) + a
// serially-dependent 4-stage shfl butterfly (~240cyc) dominate at 1 wave/SIMD.
// R8: restructure scan inner loop for latency:
//   - transposed LDS arrays [chan][l] (+4 pad) -> 8-step register batches via
//     ds_read_b128 (one lgkmcnt wait per 8 steps)
//   - butterfly deferred to end of batch: 8 independent reduction chains
//   - per-chunk parallel precompute of delta (exp2/log2 softplus) and g=delta*xs
// Semantics identical to R7 (log2-domain clamped cumsum, verified absmax 0.0039).

#define L_SEQ 2048
#define DM 512
#define DI 1024
#define DS 16
#define NXP 33
#define EPS 1e-10f
#define LOG2E 1.44269504088896340736f
#define LN2 0.69314718055994530942f
#define LOG2EPS -33.219280948873623478f  // log2(1e-10)

typedef __hip_bfloat16 bf16;

__device__ __forceinline__ float ldf(const float* p) { return *p; }
__device__ __forceinline__ float ldf(const bf16* p) { return __bfloat162float(*p); }

struct alignas(8) bf16x4 { bf16 x, y, z, w; };

__device__ __forceinline__ float4 ld4(const float* p) { return *(const float4*)p; }
__device__ __forceinline__ float4 ld4(const bf16* p) {
  bf16x4 v = *(const bf16x4*)p;
  return make_float4(__bfloat162float(v.x), __bfloat162float(v.y),
                     __bfloat162float(v.z), __bfloat162float(v.w));
}
__device__ __forceinline__ void st4(float* p, float4 v) { *(float4*)p = v; }
__device__ __forceinline__ void st4(bf16* p, float4 v) {
  bf16x4 o;
  o.x = __float2bfloat16(v.x); o.y = __float2bfloat16(v.y);
  o.z = __float2bfloat16(v.z); o.w = __float2bfloat16(v.w);
  *(bf16x4*)p = o;
}
__device__ __forceinline__ void st1(float* p, float v) { *p = v; }
__device__ __forceinline__ void st1(bf16* p, float v) { *p = __float2bfloat16(v); }

__device__ __forceinline__ float fexp2(float x) { return __builtin_amdgcn_exp2f(x); }
__device__ __forceinline__ float frcp(float x) { return __builtin_amdgcn_rcpf(x); }

// C[M,N] = A[M,K] @ B[K,N] with explicit leading dims. M,N mult of 64, K mult of 16.
template <typename TA, typename TB, typename TC>
__global__ __launch_bounds__(256)
void gemm_tiled(const TA* __restrict__ A, const TB* __restrict__ B,
                TC* __restrict__ C, int M, int N, int K,
                int lda, int ldb, int ldc) {
  __shared__ __align__(16) float As[16][68];
  __shared__ __align__(16) float Bs[16][68];
  const int tid = threadIdx.x;
  const int tx = tid & 15, ty = tid >> 4;
  const int row0 = blockIdx.y * 64, col0 = blockIdx.x * 64;
  float acc[4][4] = {};
  for (int k0 = 0; k0 < K; k0 += 16) {
#pragma unroll
    for (int j = 0; j < 4; ++j) {
      int i = tid + j * 256;
      int m = i >> 4, kk = i & 15;
      As[kk][m] = ldf(A + (size_t)(row0 + m) * lda + (k0 + kk));
    }
#pragma unroll
    for (int j = 0; j < 4; ++j) {
      int i = tid + j * 256;
      int n = i & 63, kk = i >> 6;
      Bs[kk][n] = ldf(B + (size_t)(k0 + kk) * ldb + (col0 + n));
    }
    __syncthreads();
#pragma unroll
    for (int kk = 0; kk < 16; ++kk) {
      float4 a4 = *(const float4*)&As[kk][ty * 4];
      float4 b4 = *(const float4*)&Bs[kk][tx * 4];
      float av[4] = {a4.x, a4.y, a4.z, a4.w};
      float bv[4] = {b4.x, b4.y, b4.z, b4.w};
#pragma unroll
      for (int i = 0; i < 4; ++i)
#pragma unroll
        for (int j = 0; j < 4; ++j)
          acc[i][j] = fmaf(av[i], bv[j], acc[i][j]);
    }
    __syncthreads();
  }
#pragma unroll
  for (int i = 0; i < 4; ++i) {
    float4 v = make_float4(acc[i][0], acc[i][1], acc[i][2], acc[i][3]);
    st4(C + (size_t)(row0 + ty * 4 + i) * ldc + (col0 + tx * 4), v);
  }
}

// Depthwise causal conv (width 4) + bias + SiLU: buf0(x-pre) -> buf1(xs).
template <typename T>
__global__ __launch_bounds__(256)
void conv_silu_kernel(const T* __restrict__ xpre, const float* __restrict__ conv_w,
                      const float* __restrict__ conv_b, T* __restrict__ xs) {
  int idx = blockIdx.x * 256 + threadIdx.x;  // l*1024 + d
  int d = idx & (DI - 1);
  int l = idx >> 10;
  float acc = conv_b[d];
#pragma unroll
  for (int k = 0; k < 4; ++k) {
    int ls = l + k - 3;
    if (ls >= 0) acc = fmaf(ldf(xpre + (size_t)ls * DI + d), conv_w[d * 4 + k], acc);
  }
  st1(xs + idx, acc / (1.f + __expf(-acc)));
}

// xp[l, 0:33] = xs[l, :] @ W_xproj
template <typename T>
__global__ __launch_bounds__(64)
void xproj_kernel(const T* __restrict__ xs, const float* __restrict__ W_xproj,
                  float* __restrict__ xp) {
  __shared__ float row[DI];
  int l = blockIdx.x;
  for (int i = threadIdx.x; i < DI; i += 64) row[i] = ldf(xs + (size_t)l * DI + i);
  __syncthreads();
  int j = threadIdx.x;
  if (j < NXP) {
    float acc = 0.f;
#pragma unroll 8
    for (int i = 0; i < DI; ++i)
      acc = fmaf(row[i], W_xproj[i * NXP + j], acc);
    xp[l * NXP + j] = acc;
  }
}

// Sequential scan. One wave/block; 4 d-channels x 16 states. log2-domain
// clamped cumsum (semantics == R6/R7, verified). Latency-restructured:
// transposed padded LDS, 8-step register batches, deferred butterfly.
#define LCHUNK 128
#define PSTR 132   // padded row stride (128+4): breaks pow2 bank aliasing
#define UB 8       // steps per register batch
template <typename T>
__global__ __launch_bounds__(64)
void scan_kernel(T* __restrict__ xsbuf, const T* __restrict__ zbuf,
                 const float* __restrict__ xp,
                 const float* __restrict__ dt_w, const float* __restrict__ dt_b,
                 const float* __restrict__ A_log, const float* __restrict__ Dvec) {
  __shared__ __align__(16) float sxpT[NXP * PSTR];   // [j][l] transposed xp
  __shared__ __align__(16) float sdtT[4 * PSTR];     // delta per (c,l)
  __shared__ __align__(16) float sgT[4 * PSTR];      // delta*xs
  __shared__ __align__(16) float sxsT[4 * PSTR];     // xs
  __shared__ __align__(16) float szT[4 * PSTR];      // z
  __shared__ __align__(16) float sys[LCHUNK * 4];    // gated output staging
  const int lane = threadIdx.x;
  const int s = lane & 15, dl = lane >> 4;
  const int d0 = blockIdx.x * 4;
  const float As2 = -expf(A_log[s]) * LOG2E;  // u2 = dt*As2 (log2 units)
  const float Dd = Dvec[d0 + dl];
  float dtw[4], dtb[4];
#pragma unroll
  for (int c = 0; c < 4; ++c) {
    dtw[c] = dt_w[d0 + c];
    dtb[c] = dt_b[d0 + c];
  }
  float cs2 = 0.f, S = 0.f, rcp_prev = 1.f;  // 1/max(A_shift,EPS), A_shift[0]=1
  for (int l0 = 0; l0 < L_SEQ; l0 += LCHUNK) {
    // Phase A: stage xp (transposed) and xs/z (transposed) from global.
    for (int idx = lane; idx < NXP * LCHUNK; idx += 64) {
      int j = idx >> 7, l = idx & 127;
      sxpT[j * PSTR + l] = xp[(l0 + l) * NXP + j];
    }
    for (int i = lane; i < LCHUNK; i += 64) {
      float4 xv4 = ld4(xsbuf + (size_t)(l0 + i) * DI + d0);
      float4 zv4 = ld4(zbuf + (size_t)(l0 + i) * DI + d0);
      sxsT[0 * PSTR + i] = xv4.x; sxsT[1 * PSTR + i] = xv4.y;
      sxsT[2 * PSTR + i] = xv4.z; sxsT[3 * PSTR + i] = xv4.w;
      szT[0 * PSTR + i] = zv4.x; szT[1 * PSTR + i] = zv4.y;
      szT[2 * PSTR + i] = zv4.z; szT[3 * PSTR + i] = zv4.w;
    }
    __syncthreads();
    // Phase B: delta = softplus(x0*dtw+dtb) via exp2/log2; g = delta*xs.
    for (int i = lane; i < LCHUNK; i += 64) {
      float x0 = sxpT[0 * PSTR + i];
#pragma unroll
      for (int c = 0; c < 4; ++c) {
        float a = fmaf(x0, dtw[c], dtb[c]);
        float dt = __log2f(1.f + fexp2(a * LOG2E)) * LN2;
        sdtT[c * PSTR + i] = dt;
        sgT[c * PSTR + i] = dt * sxsT[c * PSTR + i];
      }
    }
    __syncthreads();
    // Main loop: 8-step register batches.
    for (int i = 0; i < LCHUNK; i += UB) {
      float bp[UB], cp[UB], dt[UB], g[UB], contrib[UB];
#pragma unroll
      for (int k = 0; k < UB; ++k) bp[k] = sxpT[(1 + s) * PSTR + i + k];
#pragma unroll
      for (int k = 0; k < UB; ++k) cp[k] = sxpT[(17 + s) * PSTR + i + k];
#pragma unroll
      for (int k = 0; k < UB; ++k) dt[k] = sdtT[dl * PSTR + i + k];
#pragma unroll
      for (int k = 0; k < UB; ++k) g[k] = sgT[dl * PSTR + i + k];
#pragma unroll
      for (int k = 0; k < UB; ++k) {
        float u2 = dt[k] * As2;
        cs2 += fmaxf(u2, LOG2EPS);
        float acum = fexp2(cs2);
        S = fmaf(g[k] * bp[k], rcp_prev, S);      // uses previous step's acum
        rcp_prev = frcp(fmaxf(acum, EPS));
        float h = acum * S * frcp(fmaxf(fexp2(u2), EPS));
        contrib[k] = cp[k] * h;
      }
#pragma unroll
      for (int k = 0; k < UB; ++k) {
        contrib[k] += __shfl_xor(contrib[k], 8);
        contrib[k] += __shfl_xor(contrib[k], 4);
        contrib[k] += __shfl_xor(contrib[k], 2);
        contrib[k] += __shfl_xor(contrib[k], 1);
      }
      if (s == 0) {
#pragma unroll
        for (int k = 0; k < UB; ++k) {
          float xv = sxsT[dl * PSTR + i + k];
          float zv = szT[dl * PSTR + i + k];
          float yv = contrib[k] + Dd * xv;
          sys[(i + k) * 4 + dl] = yv * zv * frcp(1.f + fexp2(-zv * LOG2E));
        }
      }
    }
    __syncthreads();
    for (int i = lane; i < LCHUNK; i += 64)
      st4(xsbuf + (size_t)(l0 + i) * DI + d0, *(const float4*)&sys[i * 4]);
    __syncthreads();
  }
}

template <typename T>
static void run_pipeline(const float* x, const float* W_in, const float* conv_w,
                         const float* conv_b, const float* W_xproj, const float* dt_w,
                         const float* dt_b, const float* A_log, const float* Dvec,
                         const float* W_out, float* out, void* ws, hipStream_t stream) {
  const size_t nbuf = (size_t)L_SEQ * DI;
  T* buf0 = (T*)ws;
  T* buf1 = buf0 + nbuf;
  float* xp = (float*)(buf1 + nbuf);

  // 1a) buf0 = x @ W_in[:, 0:1024]   (x-half)
  gemm_tiled<float, float, T><<<dim3(DI / 64, L_SEQ / 64), 256, 0, stream>>>(
      x, W_in, buf0, L_SEQ, DI, DM, DM, 2 * DI, DI);
  // 2) conv + silu -> buf1 (xs)
  conv_silu_kernel<T><<<L_SEQ * DI / 256, 256, 0, stream>>>(buf0, conv_w, conv_b, buf1);
  // 3) xp = xs @ W_xproj
  xproj_kernel<T><<<L_SEQ, 64, 0, stream>>>(buf1, W_xproj, xp);
  // 1b) buf0 = x @ W_in[:, 1024:2048]  (z-half; x-pre is dead now)
  gemm_tiled<float, float, T><<<dim3(DI / 64, L_SEQ / 64), 256, 0, stream>>>(
      x, W_in + DI, buf0, L_SEQ, DI, DM, DM, 2 * DI, DI);
  // 4) scan + gate: ys written in place into buf1
  scan_kernel<T><<<DI / 4, 64, 0, stream>>>(buf1, buf0, xp, dt_w, dt_b, A_log, Dvec);
  // 5) out = ys @ W_out  (2048 x 512 x 1024), FP32 store
  gemm_tiled<T, float, float><<<dim3(DM / 64, L_SEQ / 64), 256, 0, stream>>>(
      buf1, W_out, out, L_SEQ, DM, DI, DI, DM, DM);
}

extern "C" void kernel_launch(void* const* d_in, const int* in_sizes, int n_in,
                              void* d_out, int out_size, void* d_ws, size_t ws_size,
                              hipStream_t stream) {
  const float* x       = (const float*)d_in[0];
  const float* W_in    = (const float*)d_in[1];
  const float* conv_w  = (const float*)d_in[2];
  const float* conv_b  = (const float*)d_in[3];
  const float* W_xproj = (const float*)d_in[4];
  const float* dt_w    = (const float*)d_in[5];
  const float* dt_b    = (const float*)d_in[6];
  const float* A_log   = (const float*)d_in[7];
  const float* Dvec    = (const float*)d_in[8];
  const float* W_out   = (const float*)d_in[9];
  float* out = (float*)d_out;

  const size_t nbuf = (size_t)L_SEQ * DI;
  const size_t need_f32  = 2 * nbuf * sizeof(float) + (size_t)L_SEQ * NXP * sizeof(float);
  const size_t need_bf16 = 2 * nbuf * sizeof(bf16)  + (size_t)L_SEQ * NXP * sizeof(float);

  if (ws_size >= need_f32) {
    run_pipeline<float>(x, W_in, conv_w, conv_b, W_xproj, dt_w, dt_b, A_log, Dvec,
                        W_out, out, d_ws, stream);
  } else if (ws_size >= need_bf16) {
    run_pipeline<bf16>(x, W_in, conv_w, conv_b, W_xproj, dt_w, dt_b, A_log, Dvec,
                       W_out, out, d_ws, stream);
  }
}

// Round 9
// 518.215 us; speedup vs baseline: 2.0915x; 1.0095x over previous
//
#include <hip/hip_runtime.h>
#include <hip/hip_bf16.h>

// SelectiveSSM: B=1, L=2048, D_MODEL=512, D_INNER=1024, D_STATE=16, D_CONV=4
// ESTABLISHED: inputs fp32, d_out fp32. R8: 523 us total, scan 273 us,
// VALUBusy 11% -> serial chain still carries exp2/rcp latency (~133 cyc/step):
// rcp_prev computed between S-updates => transcendentals scheduled inside the
// loop-carried chain. R9: phase-split batches (UB=16), bit-identical math:
//   P1 cs2 prefix (serial add, 4cyc/step) -> P2 all exp2/rcp/gb off-chain
//   (independent, pipelined) -> P3 S fmaf-chain (4cyc/step) -> P4 butterfly.
// Expect ~20-30 cyc/step.

#define L_SEQ 2048
#define DM 512
#define DI 1024
#define DS 16
#define NXP 33
#define EPS 1e-10f
#define LOG2E 1.44269504088896340736f
#define LN2 0.69314718055994530942f
#define LOG2EPS -33.219280948873623478f  // log2(1e-10)

typedef __hip_bfloat16 bf16;

__device__ __forceinline__ float ldf(const float* p) { return *p; }
__device__ __forceinline__ float ldf(const bf16* p) { return __bfloat162float(*p); }

struct alignas(8) bf16x4 { bf16 x, y, z, w; };

__device__ __forceinline__ float4 ld4(const float* p) { return *(const float4*)p; }
__device__ __forceinline__ float4 ld4(const bf16* p) {
  bf16x4 v = *(const bf16x4*)p;
  return make_float4(__bfloat162float(v.x), __bfloat162float(v.y),
                     __bfloat162float(v.z), __bfloat162float(v.w));
}
__device__ __forceinline__ void st4(float* p, float4 v) { *(float4*)p = v; }
__device__ __forceinline__ void st4(bf16* p, float4 v) {
  bf16x4 o;
  o.x = __float2bfloat16(v.x); o.y = __float2bfloat16(v.y);
  o.z = __float2bfloat16(v.z); o.w = __float2bfloat16(v.w);
  *(bf16x4*)p = o;
}
__device__ __forceinline__ void st1(float* p, float v) { *p = v; }
__device__ __forceinline__ void st1(bf16* p, float v) { *p = __float2bfloat16(v); }

__device__ __forceinline__ float fexp2(float x) { return __builtin_amdgcn_exp2f(x); }
__device__ __forceinline__ float frcp(float x) { return __builtin_amdgcn_rcpf(x); }

// C[M,N] = A[M,K] @ B[K,N] with explicit leading dims. M,N mult of 64, K mult of 16.
template <typename TA, typename TB, typename TC>
__global__ __launch_bounds__(256)
void gemm_tiled(const TA* __restrict__ A, const TB* __restrict__ B,
                TC* __restrict__ C, int M, int N, int K,
                int lda, int ldb, int ldc) {
  __shared__ __align__(16) float As[16][68];
  __shared__ __align__(16) float Bs[16][68];
  const int tid = threadIdx.x;
  const int tx = tid & 15, ty = tid >> 4;
  const int row0 = blockIdx.y * 64, col0 = blockIdx.x * 64;
  float acc[4][4] = {};
  for (int k0 = 0; k0 < K; k0 += 16) {
#pragma unroll
    for (int j = 0; j < 4; ++j) {
      int i = tid + j * 256;
      int m = i >> 4, kk = i & 15;
      As[kk][m] = ldf(A + (size_t)(row0 + m) * lda + (k0 + kk));
    }
#pragma unroll
    for (int j = 0; j < 4; ++j) {
      int i = tid + j * 256;
      int n = i & 63, kk = i >> 6;
      Bs[kk][n] = ldf(B + (size_t)(k0 + kk) * ldb + (col0 + n));
    }
    __syncthreads();
#pragma unroll
    for (int kk = 0; kk < 16; ++kk) {
      float4 a4 = *(const float4*)&As[kk][ty * 4];
      float4 b4 = *(const float4*)&Bs[kk][tx * 4];
      float av[4] = {a4.x, a4.y, a4.z, a4.w};
      float bv[4] = {b4.x, b4.y, b4.z, b4.w};
#pragma unroll
      for (int i = 0; i < 4; ++i)
#pragma unroll
        for (int j = 0; j < 4; ++j)
          acc[i][j] = fmaf(av[i], bv[j], acc[i][j]);
    }
    __syncthreads();
  }
#pragma unroll
  for (int i = 0; i < 4; ++i) {
    float4 v = make_float4(acc[i][0], acc[i][1], acc[i][2], acc[i][3]);
    st4(C + (size_t)(row0 + ty * 4 + i) * ldc + (col0 + tx * 4), v);
  }
}

// Depthwise causal conv (width 4) + bias + SiLU: buf0(x-pre) -> buf1(xs).
template <typename T>
__global__ __launch_bounds__(256)
void conv_silu_kernel(const T* __restrict__ xpre, const float* __restrict__ conv_w,
                      const float* __restrict__ conv_b, T* __restrict__ xs) {
  int idx = blockIdx.x * 256 + threadIdx.x;  // l*1024 + d
  int d = idx & (DI - 1);
  int l = idx >> 10;
  float acc = conv_b[d];
#pragma unroll
  for (int k = 0; k < 4; ++k) {
    int ls = l + k - 3;
    if (ls >= 0) acc = fmaf(ldf(xpre + (size_t)ls * DI + d), conv_w[d * 4 + k], acc);
  }
  st1(xs + idx, acc / (1.f + __expf(-acc)));
}

// xp[l, 0:33] = xs[l, :] @ W_xproj
template <typename T>
__global__ __launch_bounds__(64)
void xproj_kernel(const T* __restrict__ xs, const float* __restrict__ W_xproj,
                  float* __restrict__ xp) {
  __shared__ float row[DI];
  int l = blockIdx.x;
  for (int i = threadIdx.x; i < DI; i += 64) row[i] = ldf(xs + (size_t)l * DI + i);
  __syncthreads();
  int j = threadIdx.x;
  if (j < NXP) {
    float acc = 0.f;
#pragma unroll 8
    for (int i = 0; i < DI; ++i)
      acc = fmaf(row[i], W_xproj[i * NXP + j], acc);
    xp[l * NXP + j] = acc;
  }
}

// Sequential scan. One wave/block; 4 d-channels x 16 states. log2-domain
// clamped cumsum (bit-identical dataflow to R8). Phase-split UB=16 batches:
// serial chains are only cs2-adds and S-fmafs (4cyc each); all exp2/rcp
// off-chain and pipelined; butterfly batched at end.
#define LCHUNK 128
#define PSTR 132   // padded row stride (128+4)
#define UB 16      // steps per register batch
template <typename T>
__global__ __launch_bounds__(64)
void scan_kernel(T* __restrict__ xsbuf, const T* __restrict__ zbuf,
                 const float* __restrict__ xp,
                 const float* __restrict__ dt_w, const float* __restrict__ dt_b,
                 const float* __restrict__ A_log, const float* __restrict__ Dvec) {
  __shared__ __align__(16) float sxpT[NXP * PSTR];   // [j][l] transposed xp
  __shared__ __align__(16) float sdtT[4 * PSTR];     // delta per (c,l)
  __shared__ __align__(16) float sgT[4 * PSTR];      // delta*xs
  __shared__ __align__(16) float sxsT[4 * PSTR];     // xs
  __shared__ __align__(16) float szT[4 * PSTR];      // z
  __shared__ __align__(16) float sys[LCHUNK * 4];    // gated output staging
  const int lane = threadIdx.x;
  const int s = lane & 15, dl = lane >> 4;
  const int d0 = blockIdx.x * 4;
  const float As2 = -expf(A_log[s]) * LOG2E;  // u2 = dt*As2 (log2 units)
  const float Dd = Dvec[d0 + dl];
  float dtw[4], dtb[4];
#pragma unroll
  for (int c = 0; c < 4; ++c) {
    dtw[c] = dt_w[d0 + c];
    dtb[c] = dt_b[d0 + c];
  }
  float cs2 = 0.f, S = 0.f, rcp_prev = 1.f;  // 1/max(A_shift,EPS), A_shift[0]=1
  for (int l0 = 0; l0 < L_SEQ; l0 += LCHUNK) {
    // Phase A: stage xp (transposed) and xs/z (transposed) from global.
    for (int idx = lane; idx < NXP * LCHUNK; idx += 64) {
      int j = idx >> 7, l = idx & 127;
      sxpT[j * PSTR + l] = xp[(l0 + l) * NXP + j];
    }
    for (int i = lane; i < LCHUNK; i += 64) {
      float4 xv4 = ld4(xsbuf + (size_t)(l0 + i) * DI + d0);
      float4 zv4 = ld4(zbuf + (size_t)(l0 + i) * DI + d0);
      sxsT[0 * PSTR + i] = xv4.x; sxsT[1 * PSTR + i] = xv4.y;
      sxsT[2 * PSTR + i] = xv4.z; sxsT[3 * PSTR + i] = xv4.w;
      szT[0 * PSTR + i] = zv4.x; szT[1 * PSTR + i] = zv4.y;
      szT[2 * PSTR + i] = zv4.z; szT[3 * PSTR + i] = zv4.w;
    }
    __syncthreads();
    // Phase B: delta = softplus(x0*dtw+dtb) via exp2/log2; g = delta*xs.
    for (int i = lane; i < LCHUNK; i += 64) {
      float x0 = sxpT[0 * PSTR + i];
#pragma unroll
      for (int c = 0; c < 4; ++c) {
        float a = fmaf(x0, dtw[c], dtb[c]);
        float dt = __log2f(1.f + fexp2(a * LOG2E)) * LN2;
        sdtT[c * PSTR + i] = dt;
        sgT[c * PSTR + i] = dt * sxsT[c * PSTR + i];
      }
    }
    __syncthreads();
    // Main loop: UB-step phase-split register batches.
    for (int i = 0; i < LCHUNK; i += UB) {
      float gb[UB], cp[UB], u2[UB], csv[UB], acum[UB], rcpA[UB], rcpU[UB],
            contrib[UB];
      // loads (b128-vectorizable; dt/g are 16-lane broadcasts)
#pragma unroll
      for (int k = 0; k < UB; ++k) {
        float dt = sdtT[dl * PSTR + i + k];
        u2[k] = dt * As2;
      }
#pragma unroll
      for (int k = 0; k < UB; ++k)
        gb[k] = sgT[dl * PSTR + i + k] * sxpT[(1 + s) * PSTR + i + k];
#pragma unroll
      for (int k = 0; k < UB; ++k) cp[k] = sxpT[(17 + s) * PSTR + i + k];
      // P1: cs2 prefix (serial add chain only)
#pragma unroll
      for (int k = 0; k < UB; ++k) {
        cs2 += fmaxf(u2[k], LOG2EPS);
        csv[k] = cs2;
      }
      // P2: transcendentals, fully independent
#pragma unroll
      for (int k = 0; k < UB; ++k) acum[k] = fexp2(csv[k]);
#pragma unroll
      for (int k = 0; k < UB; ++k) rcpA[k] = frcp(fmaxf(acum[k], EPS));
#pragma unroll
      for (int k = 0; k < UB; ++k) rcpU[k] = frcp(fmaxf(fexp2(u2[k]), EPS));
      // P3: S fmaf chain (serial), contrib off-chain
#pragma unroll
      for (int k = 0; k < UB; ++k) {
        S = fmaf(gb[k], rcp_prev, S);
        rcp_prev = rcpA[k];
        contrib[k] = cp[k] * (acum[k] * S * rcpU[k]);
      }
      // P4: batched butterfly (independent chains)
#pragma unroll
      for (int k = 0; k < UB; ++k) {
        contrib[k] += __shfl_xor(contrib[k], 8);
        contrib[k] += __shfl_xor(contrib[k], 4);
        contrib[k] += __shfl_xor(contrib[k], 2);
        contrib[k] += __shfl_xor(contrib[k], 1);
      }
      if (s == 0) {
#pragma unroll
        for (int k = 0; k < UB; ++k) {
          float xv = sxsT[dl * PSTR + i + k];
          float zv = szT[dl * PSTR + i + k];
          float yv = contrib[k] + Dd * xv;
          sys[(i + k) * 4 + dl] = yv * zv * frcp(1.f + fexp2(-zv * LOG2E));
        }
      }
    }
    __syncthreads();
    for (int i = lane; i < LCHUNK; i += 64)
      st4(xsbuf + (size_t)(l0 + i) * DI + d0, *(const float4*)&sys[i * 4]);
    __syncthreads();
  }
}

template <typename T>
static void run_pipeline(const float* x, const float* W_in, const float* conv_w,
                         const float* conv_b, const float* W_xproj, const float* dt_w,
                         const float* dt_b, const float* A_log, const float* Dvec,
                         const float* W_out, float* out, void* ws, hipStream_t stream) {
  const size_t nbuf = (size_t)L_SEQ * DI;
  T* buf0 = (T*)ws;
  T* buf1 = buf0 + nbuf;
  float* xp = (float*)(buf1 + nbuf);

  // 1a) buf0 = x @ W_in[:, 0:1024]   (x-half)
  gemm_tiled<float, float, T><<<dim3(DI / 64, L_SEQ / 64), 256, 0, stream>>>(
      x, W_in, buf0, L_SEQ, DI, DM, DM, 2 * DI, DI);
  // 2) conv + silu -> buf1 (xs)
  conv_silu_kernel<T><<<L_SEQ * DI / 256, 256, 0, stream>>>(buf0, conv_w, conv_b, buf1);
  // 3) xp = xs @ W_xproj
  xproj_kernel<T><<<L_SEQ, 64, 0, stream>>>(buf1, W_xproj, xp);
  // 1b) buf0 = x @ W_in[:, 1024:2048]  (z-half; x-pre is dead now)
  gemm_tiled<float, float, T><<<dim3(DI / 64, L_SEQ / 64), 256, 0, stream>>>(
      x, W_in + DI, buf0, L_SEQ, DI, DM, DM, 2 * DI, DI);
  // 4) scan + gate: ys written in place into buf1
  scan_kernel<T><<<DI / 4, 64, 0, stream>>>(buf1, buf0, xp, dt_w, dt_b, A_log, Dvec);
  // 5) out = ys @ W_out  (2048 x 512 x 1024), FP32 store
  gemm_tiled<T, float, float><<<dim3(DM / 64, L_SEQ / 64), 256, 0, stream>>>(
      buf1, W_out, out, L_SEQ, DM, DI, DI, DM, DM);
}

extern "C" void kernel_launch(void* const* d_in, const int* in_sizes, int n_in,
                              void* d_out, int out_size, void* d_ws, size_t ws_size,
                              hipStream_t stream) {
  const float* x       = (const float*)d_in[0];
  const float* W_in    = (const float*)d_in[1];
  const float* conv_w  = (const float*)d_in[2];
  const float* conv_b  = (const float*)d_in[3];
  const float* W_xproj = (const float*)d_in[4];
  const float* dt_w    = (const float*)d_in[5];
  const float* dt_b    = (const float*)d_in[6];
  const float* A_log   = (const float*)d_in[7];
  const float* Dvec    = (const float*)d_in[8];
  const float* W_out   = (const float*)d_in[9];
  float* out = (float*)d_out;

  const size_t nbuf = (size_t)L_SEQ * DI;
  const size_t need_f32  = 2 * nbuf * sizeof(float) + (size_t)L_SEQ * NXP * sizeof(float);
  const size_t need_bf16 = 2 * nbuf * sizeof(bf16)  + (size_t)L_SEQ * NXP * sizeof(float);

  if (ws_size >= need_f32) {
    run_pipeline<float>(x, W_in, conv_w, conv_b, W_xproj, dt_w, dt_b, A_log, Dvec,
                        W_out, out, d_ws, stream);
  } else if (ws_size >= need_bf16) {
    run_pipeline<bf16>(x, W_in, conv_w, conv_b, W_xproj, dt_w, dt_b, A_log, Dvec,
                       W_out, out, d_ws, stream);
  }
}

// Round 10
// 426.735 us; speedup vs baseline: 2.5398x; 1.2144x over previous
//
#include <hip/hip_runtime.h>
#include <hip/hip_bf16.h>

// SelectiveSSM: B=1, L=2048, D_MODEL=512, D_INNER=1024, D_STATE=16, D_CONV=4
// ESTABLISHED: inputs fp32, d_out fp32, ws_size >= 17.05MB.
// R10: MFMA GEMMs. R9 showed scan is staging-latency-bound (~5000cyc/batch vs
// ~500 compute; FETCH 66.7MB = 256 blocks re-reading xp) — defer to R11.
// This round: the 3 fp32 vector GEMMs (~220us, MfmaUtil=0) -> bf16 MFMA:
//   cast x->bf16, transpose-cast W_in/W_out to B^T bf16 form, 64x64-tile
//   mfma_f32_16x16x32_bf16 GEMM (A[m=lane&15][k=quad*8+j], BT row-reads,
//   C/D col=lane&15 row=quad*4+reg — guide-verified mappings).
// buf0/buf1 switch to bf16 (ws total 13.3MB, fits proven budget).
//
// ws layout (bytes):
//   buf0  bf16[2048][1024]  @ 0         (xz x-half, later z-half)
//   buf1  bf16[2048][1024]  @ 4MB       (xs, later gated ys)
//   xbf   bf16[2048][512]   @ 8MB       (x cast)
//   WinT  bf16[2048][512]   @ 10MB      (W_in^T cast)
//   WoutT bf16[512][1024]   @ 12MB      (W_out^T cast)
//   xp    f32 [2048][33]    @ 13MB

#define L_SEQ 2048
#define DM 512
#define DI 1024
#define DS 16
#define NXP 33
#define EPS 1e-10f
#define LOG2E 1.44269504088896340736f
#define LN2 0.69314718055994530942f
#define LOG2EPS -33.219280948873623478f  // log2(1e-10)

typedef __hip_bfloat16 bf16;
typedef __attribute__((ext_vector_type(8))) short bf16x8v;  // 8 bf16 (4 VGPRs)
typedef __attribute__((ext_vector_type(4))) float f32x4v;   // MFMA acc

__device__ __forceinline__ float ldf(const float* p) { return *p; }
__device__ __forceinline__ float ldf(const bf16* p) { return __bfloat162float(*p); }

struct alignas(8) bf16x4 { bf16 x, y, z, w; };

__device__ __forceinline__ float4 ld4(const float* p) { return *(const float4*)p; }
__device__ __forceinline__ float4 ld4(const bf16* p) {
  bf16x4 v = *(const bf16x4*)p;
  return make_float4(__bfloat162float(v.x), __bfloat162float(v.y),
                     __bfloat162float(v.z), __bfloat162float(v.w));
}
__device__ __forceinline__ void st4(float* p, float4 v) { *(float4*)p = v; }
__device__ __forceinline__ void st4(bf16* p, float4 v) {
  bf16x4 o;
  o.x = __float2bfloat16(v.x); o.y = __float2bfloat16(v.y);
  o.z = __float2bfloat16(v.z); o.w = __float2bfloat16(v.w);
  *(bf16x4*)p = o;
}
__device__ __forceinline__ void st1(float* p, float v) { *p = v; }
__device__ __forceinline__ void st1(bf16* p, float v) { *p = __float2bfloat16(v); }

__device__ __forceinline__ float fexp2(float x) { return __builtin_amdgcn_exp2f(x); }
__device__ __forceinline__ float frcp(float x) { return __builtin_amdgcn_rcpf(x); }

// ---------- pre-pass casts ----------

// x (fp32, n*4 elems) -> bf16
__global__ __launch_bounds__(256)
void cast_kernel(const float* __restrict__ src, bf16* __restrict__ dst) {
  size_t i = (size_t)(blockIdx.x * 256 + threadIdx.x) * 4;
  st4(dst + i, *(const float4*)(src + i));
}

// W[R][C] fp32 -> WT[C][R] bf16, 32x32 LDS tiles. grid (C/32, R/32), 256 thr.
__global__ __launch_bounds__(256)
void transpose_cast_kernel(const float* __restrict__ W, bf16* __restrict__ WT,
                           int R, int C) {
  __shared__ float tile[32][33];
  int c0 = blockIdx.x * 32, r0 = blockIdx.y * 32;
  int tx = threadIdx.x & 31, ty = threadIdx.x >> 5;  // ty 0..7
#pragma unroll
  for (int i = 0; i < 4; ++i) {
    int rr = ty + i * 8;
    tile[rr][tx] = W[(size_t)(r0 + rr) * C + c0 + tx];
  }
  __syncthreads();
#pragma unroll
  for (int i = 0; i < 4; ++i) {
    int cc = ty + i * 8;
    WT[(size_t)(c0 + cc) * R + r0 + tx] = __float2bfloat16(tile[tx][cc]);
  }
}

// ---------- MFMA GEMM: C[M][N] = A[M][K] @ BT[N][K]^T (bf16 in, TC out) ----
// 64x64 tile, 4 waves, K-step 32. LDS row stride 40 bf16 (pad vs 32).
template <typename TC>
__global__ __launch_bounds__(256)
void gemm_bt_mfma(const bf16* __restrict__ A, const bf16* __restrict__ BT,
                  TC* __restrict__ C, int M, int N, int K, int ldc) {
  __shared__ __align__(16) bf16 As[64 * 40];
  __shared__ __align__(16) bf16 Bs[64 * 40];
  const int tid = threadIdx.x;
  const int wave = tid >> 6, lane = tid & 63;
  const int q = lane >> 4, r = lane & 15;
  const int row0 = blockIdx.y * 64, col0 = blockIdx.x * 64;
  const int srow = tid >> 2, sseg = tid & 3;  // staging: 64 rows x 4 segs of 8
  f32x4v acc[4] = {};
  for (int k0 = 0; k0 < K; k0 += 32) {
    uint4 av = *(const uint4*)(A + (size_t)(row0 + srow) * K + k0 + sseg * 8);
    uint4 bv = *(const uint4*)(BT + (size_t)(col0 + srow) * K + k0 + sseg * 8);
    *(uint4*)&As[srow * 40 + sseg * 8] = av;
    *(uint4*)&Bs[srow * 40 + sseg * 8] = bv;
    __syncthreads();
    bf16x8v a = *(const bf16x8v*)&As[(wave * 16 + r) * 40 + q * 8];
#pragma unroll
    for (int j = 0; j < 4; ++j) {
      bf16x8v b = *(const bf16x8v*)&Bs[(j * 16 + r) * 40 + q * 8];
      acc[j] = __builtin_amdgcn_mfma_f32_16x16x32_bf16(a, b, acc[j], 0, 0, 0);
    }
    __syncthreads();
  }
#pragma unroll
  for (int j = 0; j < 4; ++j)
#pragma unroll
    for (int reg = 0; reg < 4; ++reg) {
      int m = row0 + wave * 16 + q * 4 + reg;
      int n = col0 + j * 16 + r;
      st1(C + (size_t)m * ldc + n, acc[j][reg]);
    }
}

// ---------- conv / xproj / scan (R9, T=bf16) ----------

template <typename T>
__global__ __launch_bounds__(256)
void conv_silu_kernel(const T* __restrict__ xpre, const float* __restrict__ conv_w,
                      const float* __restrict__ conv_b, T* __restrict__ xs) {
  int idx = blockIdx.x * 256 + threadIdx.x;  // l*1024 + d
  int d = idx & (DI - 1);
  int l = idx >> 10;
  float acc = conv_b[d];
#pragma unroll
  for (int k = 0; k < 4; ++k) {
    int ls = l + k - 3;
    if (ls >= 0) acc = fmaf(ldf(xpre + (size_t)ls * DI + d), conv_w[d * 4 + k], acc);
  }
  st1(xs + idx, acc / (1.f + __expf(-acc)));
}

template <typename T>
__global__ __launch_bounds__(64)
void xproj_kernel(const T* __restrict__ xs, const float* __restrict__ W_xproj,
                  float* __restrict__ xp) {
  __shared__ float row[DI];
  int l = blockIdx.x;
  for (int i = threadIdx.x; i < DI; i += 64) row[i] = ldf(xs + (size_t)l * DI + i);
  __syncthreads();
  int j = threadIdx.x;
  if (j < NXP) {
    float acc = 0.f;
#pragma unroll 8
    for (int i = 0; i < DI; ++i)
      acc = fmaf(row[i], W_xproj[i * NXP + j], acc);
    xp[l * NXP + j] = acc;
  }
}

#define LCHUNK 128
#define PSTR 132
#define UB 16
template <typename T>
__global__ __launch_bounds__(64)
void scan_kernel(T* __restrict__ xsbuf, const T* __restrict__ zbuf,
                 const float* __restrict__ xp,
                 const float* __restrict__ dt_w, const float* __restrict__ dt_b,
                 const float* __restrict__ A_log, const float* __restrict__ Dvec) {
  __shared__ __align__(16) float sxpT[NXP * PSTR];
  __shared__ __align__(16) float sdtT[4 * PSTR];
  __shared__ __align__(16) float sgT[4 * PSTR];
  __shared__ __align__(16) float sxsT[4 * PSTR];
  __shared__ __align__(16) float szT[4 * PSTR];
  __shared__ __align__(16) float sys[LCHUNK * 4];
  const int lane = threadIdx.x;
  const int s = lane & 15, dl = lane >> 4;
  const int d0 = blockIdx.x * 4;
  const float As2 = -expf(A_log[s]) * LOG2E;
  const float Dd = Dvec[d0 + dl];
  float dtw[4], dtb[4];
#pragma unroll
  for (int c = 0; c < 4; ++c) {
    dtw[c] = dt_w[d0 + c];
    dtb[c] = dt_b[d0 + c];
  }
  float cs2 = 0.f, S = 0.f, rcp_prev = 1.f;
  for (int l0 = 0; l0 < L_SEQ; l0 += LCHUNK) {
    for (int idx = lane; idx < NXP * LCHUNK; idx += 64) {
      int j = idx >> 7, l = idx & 127;
      sxpT[j * PSTR + l] = xp[(l0 + l) * NXP + j];
    }
    for (int i = lane; i < LCHUNK; i += 64) {
      float4 xv4 = ld4(xsbuf + (size_t)(l0 + i) * DI + d0);
      float4 zv4 = ld4(zbuf + (size_t)(l0 + i) * DI + d0);
      sxsT[0 * PSTR + i] = xv4.x; sxsT[1 * PSTR + i] = xv4.y;
      sxsT[2 * PSTR + i] = xv4.z; sxsT[3 * PSTR + i] = xv4.w;
      szT[0 * PSTR + i] = zv4.x; szT[1 * PSTR + i] = zv4.y;
      szT[2 * PSTR + i] = zv4.z; szT[3 * PSTR + i] = zv4.w;
    }
    __syncthreads();
    for (int i = lane; i < LCHUNK; i += 64) {
      float x0 = sxpT[0 * PSTR + i];
#pragma unroll
      for (int c = 0; c < 4; ++c) {
        float a = fmaf(x0, dtw[c], dtb[c]);
        float dt = __log2f(1.f + fexp2(a * LOG2E)) * LN2;
        sdtT[c * PSTR + i] = dt;
        sgT[c * PSTR + i] = dt * sxsT[c * PSTR + i];
      }
    }
    __syncthreads();
    for (int i = 0; i < LCHUNK; i += UB) {
      float gb[UB], cp[UB], u2[UB], csv[UB], acum[UB], rcpA[UB], rcpU[UB],
            contrib[UB];
#pragma unroll
      for (int k = 0; k < UB; ++k) {
        float dt = sdtT[dl * PSTR + i + k];
        u2[k] = dt * As2;
      }
#pragma unroll
      for (int k = 0; k < UB; ++k)
        gb[k] = sgT[dl * PSTR + i + k] * sxpT[(1 + s) * PSTR + i + k];
#pragma unroll
      for (int k = 0; k < UB; ++k) cp[k] = sxpT[(17 + s) * PSTR + i + k];
#pragma unroll
      for (int k = 0; k < UB; ++k) {
        cs2 += fmaxf(u2[k], LOG2EPS);
        csv[k] = cs2;
      }
#pragma unroll
      for (int k = 0; k < UB; ++k) acum[k] = fexp2(csv[k]);
#pragma unroll
      for (int k = 0; k < UB; ++k) rcpA[k] = frcp(fmaxf(acum[k], EPS));
#pragma unroll
      for (int k = 0; k < UB; ++k) rcpU[k] = frcp(fmaxf(fexp2(u2[k]), EPS));
#pragma unroll
      for (int k = 0; k < UB; ++k) {
        S = fmaf(gb[k], rcp_prev, S);
        rcp_prev = rcpA[k];
        contrib[k] = cp[k] * (acum[k] * S * rcpU[k]);
      }
#pragma unroll
      for (int k = 0; k < UB; ++k) {
        contrib[k] += __shfl_xor(contrib[k], 8);
        contrib[k] += __shfl_xor(contrib[k], 4);
        contrib[k] += __shfl_xor(contrib[k], 2);
        contrib[k] += __shfl_xor(contrib[k], 1);
      }
      if (s == 0) {
#pragma unroll
        for (int k = 0; k < UB; ++k) {
          float xv = sxsT[dl * PSTR + i + k];
          float zv = szT[dl * PSTR + i + k];
          float yv = contrib[k] + Dd * xv;
          sys[(i + k) * 4 + dl] = yv * zv * frcp(1.f + fexp2(-zv * LOG2E));
        }
      }
    }
    __syncthreads();
    for (int i = lane; i < LCHUNK; i += 64)
      st4(xsbuf + (size_t)(l0 + i) * DI + d0, *(const float4*)&sys[i * 4]);
    __syncthreads();
  }
}

extern "C" void kernel_launch(void* const* d_in, const int* in_sizes, int n_in,
                              void* d_out, int out_size, void* d_ws, size_t ws_size,
                              hipStream_t stream) {
  const float* x       = (const float*)d_in[0];
  const float* W_in    = (const float*)d_in[1];
  const float* conv_w  = (const float*)d_in[2];
  const float* conv_b  = (const float*)d_in[3];
  const float* W_xproj = (const float*)d_in[4];
  const float* dt_w    = (const float*)d_in[5];
  const float* dt_b    = (const float*)d_in[6];
  const float* A_log   = (const float*)d_in[7];
  const float* Dvec    = (const float*)d_in[8];
  const float* W_out   = (const float*)d_in[9];
  float* out = (float*)d_out;

  char* ws = (char*)d_ws;
  const size_t MB = 1024 * 1024;
  bf16* buf0  = (bf16*)(ws);                // [2048][1024]
  bf16* buf1  = (bf16*)(ws + 4 * MB);       // [2048][1024]
  bf16* xbf   = (bf16*)(ws + 8 * MB);       // [2048][512]
  bf16* WinT  = (bf16*)(ws + 10 * MB);      // [2048][512]
  bf16* WoutT = (bf16*)(ws + 12 * MB);      // [512][1024]
  float* xp   = (float*)(ws + 13 * MB);     // [2048][33]

  // 0) casts
  cast_kernel<<<(L_SEQ * DM / 4) / 256, 256, 0, stream>>>(x, xbf);
  transpose_cast_kernel<<<dim3(2 * DI / 32, DM / 32), 256, 0, stream>>>(
      W_in, WinT, DM, 2 * DI);
  transpose_cast_kernel<<<dim3(DM / 32, DI / 32), 256, 0, stream>>>(
      W_out, WoutT, DI, DM);
  // 1a) buf0 = x @ W_in[:, 0:1024]  (x-half)
  gemm_bt_mfma<bf16><<<dim3(DI / 64, L_SEQ / 64), 256, 0, stream>>>(
      xbf, WinT, buf0, L_SEQ, DI, DM, DI);
  // 2) conv + silu -> buf1 (xs)
  conv_silu_kernel<bf16><<<L_SEQ * DI / 256, 256, 0, stream>>>(buf0, conv_w, conv_b, buf1);
  // 3) xp = xs @ W_xproj
  xproj_kernel<bf16><<<L_SEQ, 64, 0, stream>>>(buf1, W_xproj, xp);
  // 1b) buf0 = x @ W_in[:, 1024:2048]  (z-half)
  gemm_bt_mfma<bf16><<<dim3(DI / 64, L_SEQ / 64), 256, 0, stream>>>(
      xbf, WinT + (size_t)DI * DM, buf0, L_SEQ, DI, DM, DI);
  // 4) scan + gate -> buf1 in place
  scan_kernel<bf16><<<DI / 4, 64, 0, stream>>>(buf1, buf0, xp, dt_w, dt_b, A_log, Dvec);
  // 5) out = ys @ W_out  (fp32 store)
  gemm_bt_mfma<float><<<dim3(DM / 64, L_SEQ / 64), 256, 0, stream>>>(
      buf1, WoutT, out, L_SEQ, DM, DI, DM);
}

// Round 11
// 278.137 us; speedup vs baseline: 3.8968x; 1.5343x over previous
//
#include <hip/hip_runtime.h>
#include <hip/hip_bf16.h>

// SelectiveSSM: B=1, L=2048, D_MODEL=512, D_INNER=1024, D_STATE=16, D_CONV=4
// ESTABLISHED: inputs fp32, d_out fp32, ws >= 17MB, MFMA GEMMs (R10, 427us).
// R11: chunk-parallel scan. The clamped log2 recurrence is two chained prefix
// sums (cs2 = sum w; S = sum v where v = g*bp*rcp(max(2^cs2_prev,EPS)));
// h = 2^cs2 * S * rcp(max(2^u2,EPS)) is elementwise. One 1024-thread block
// (16 waves) per 4-channel group; L in 4 chunks of 512; 3 passes per chunk
// (W-totals -> offsets; V-totals -> offsets; final h/contrib/gate) with
// per-lane carries across chunks. Serial chain per pass: 32 steps (was 2048).

#define L_SEQ 2048
#define DM 512
#define DI 1024
#define DS 16
#define NXP 33
#define EPS 1e-10f
#define LOG2E 1.44269504088896340736f
#define LN2 0.69314718055994530942f
#define LOG2EPS -33.219280948873623478f  // log2(1e-10)

typedef __hip_bfloat16 bf16;
typedef __attribute__((ext_vector_type(8))) short bf16x8v;  // 8 bf16 (4 VGPRs)
typedef __attribute__((ext_vector_type(4))) float f32x4v;   // MFMA acc

__device__ __forceinline__ float ldf(const float* p) { return *p; }
__device__ __forceinline__ float ldf(const bf16* p) { return __bfloat162float(*p); }

struct alignas(8) bf16x4 { bf16 x, y, z, w; };

__device__ __forceinline__ float4 ld4(const float* p) { return *(const float4*)p; }
__device__ __forceinline__ float4 ld4(const bf16* p) {
  bf16x4 v = *(const bf16x4*)p;
  return make_float4(__bfloat162float(v.x), __bfloat162float(v.y),
                     __bfloat162float(v.z), __bfloat162float(v.w));
}
__device__ __forceinline__ void st4(float* p, float4 v) { *(float4*)p = v; }
__device__ __forceinline__ void st4(bf16* p, float4 v) {
  bf16x4 o;
  o.x = __float2bfloat16(v.x); o.y = __float2bfloat16(v.y);
  o.z = __float2bfloat16(v.z); o.w = __float2bfloat16(v.w);
  *(bf16x4*)p = o;
}
__device__ __forceinline__ void st1(float* p, float v) { *p = v; }
__device__ __forceinline__ void st1(bf16* p, float v) { *p = __float2bfloat16(v); }

__device__ __forceinline__ float fexp2(float x) { return __builtin_amdgcn_exp2f(x); }
__device__ __forceinline__ float frcp(float x) { return __builtin_amdgcn_rcpf(x); }

// ---------- pre-pass casts ----------

__global__ __launch_bounds__(256)
void cast_kernel(const float* __restrict__ src, bf16* __restrict__ dst) {
  size_t i = (size_t)(blockIdx.x * 256 + threadIdx.x) * 4;
  st4(dst + i, *(const float4*)(src + i));
}

// W[R][C] fp32 -> WT[C][R] bf16, 32x32 LDS tiles. grid (C/32, R/32), 256 thr.
__global__ __launch_bounds__(256)
void transpose_cast_kernel(const float* __restrict__ W, bf16* __restrict__ WT,
                           int R, int C) {
  __shared__ float tile[32][33];
  int c0 = blockIdx.x * 32, r0 = blockIdx.y * 32;
  int tx = threadIdx.x & 31, ty = threadIdx.x >> 5;  // ty 0..7
#pragma unroll
  for (int i = 0; i < 4; ++i) {
    int rr = ty + i * 8;
    tile[rr][tx] = W[(size_t)(r0 + rr) * C + c0 + tx];
  }
  __syncthreads();
#pragma unroll
  for (int i = 0; i < 4; ++i) {
    int cc = ty + i * 8;
    WT[(size_t)(c0 + cc) * R + r0 + tx] = __float2bfloat16(tile[tx][cc]);
  }
}

// ---------- MFMA GEMM: C[M][N] = A[M][K] @ BT[N][K]^T (bf16 in, TC out) ----
template <typename TC>
__global__ __launch_bounds__(256)
void gemm_bt_mfma(const bf16* __restrict__ A, const bf16* __restrict__ BT,
                  TC* __restrict__ C, int M, int N, int K, int ldc) {
  __shared__ __align__(16) bf16 As[64 * 40];
  __shared__ __align__(16) bf16 Bs[64 * 40];
  const int tid = threadIdx.x;
  const int wave = tid >> 6, lane = tid & 63;
  const int q = lane >> 4, r = lane & 15;
  const int row0 = blockIdx.y * 64, col0 = blockIdx.x * 64;
  const int srow = tid >> 2, sseg = tid & 3;
  f32x4v acc[4] = {};
  for (int k0 = 0; k0 < K; k0 += 32) {
    uint4 av = *(const uint4*)(A + (size_t)(row0 + srow) * K + k0 + sseg * 8);
    uint4 bv = *(const uint4*)(BT + (size_t)(col0 + srow) * K + k0 + sseg * 8);
    *(uint4*)&As[srow * 40 + sseg * 8] = av;
    *(uint4*)&Bs[srow * 40 + sseg * 8] = bv;
    __syncthreads();
    bf16x8v a = *(const bf16x8v*)&As[(wave * 16 + r) * 40 + q * 8];
#pragma unroll
    for (int j = 0; j < 4; ++j) {
      bf16x8v b = *(const bf16x8v*)&Bs[(j * 16 + r) * 40 + q * 8];
      acc[j] = __builtin_amdgcn_mfma_f32_16x16x32_bf16(a, b, acc[j], 0, 0, 0);
    }
    __syncthreads();
  }
#pragma unroll
  for (int j = 0; j < 4; ++j)
#pragma unroll
    for (int reg = 0; reg < 4; ++reg) {
      int m = row0 + wave * 16 + q * 4 + reg;
      int n = col0 + j * 16 + r;
      st1(C + (size_t)m * ldc + n, acc[j][reg]);
    }
}

// ---------- conv / xproj ----------

template <typename T>
__global__ __launch_bounds__(256)
void conv_silu_kernel(const T* __restrict__ xpre, const float* __restrict__ conv_w,
                      const float* __restrict__ conv_b, T* __restrict__ xs) {
  int idx = blockIdx.x * 256 + threadIdx.x;  // l*1024 + d
  int d = idx & (DI - 1);
  int l = idx >> 10;
  float acc = conv_b[d];
#pragma unroll
  for (int k = 0; k < 4; ++k) {
    int ls = l + k - 3;
    if (ls >= 0) acc = fmaf(ldf(xpre + (size_t)ls * DI + d), conv_w[d * 4 + k], acc);
  }
  st1(xs + idx, acc / (1.f + __expf(-acc)));
}

template <typename T>
__global__ __launch_bounds__(64)
void xproj_kernel(const T* __restrict__ xs, const float* __restrict__ W_xproj,
                  float* __restrict__ xp) {
  __shared__ float row[DI];
  int l = blockIdx.x;
  for (int i = threadIdx.x; i < DI; i += 64) row[i] = ldf(xs + (size_t)l * DI + i);
  __syncthreads();
  int j = threadIdx.x;
  if (j < NXP) {
    float acc = 0.f;
#pragma unroll 8
    for (int i = 0; i < DI; ++i)
      acc = fmaf(row[i], W_xproj[i * NXP + j], acc);
    xp[l * NXP + j] = acc;
  }
}

// ---------- chunk-parallel scan ----------
// 1024 threads = 16 waves; each wave owns SPW=32 steps of the LC=512 chunk.
// Lane layout: s = lane&15 (state), dl = lane>>4 (channel within d0..d0+3).
#define LC 512
#define NW 16
#define SPW 32
#define PS 513  // padded LDS row stride

__global__ __launch_bounds__(1024)
void scan_kernel(bf16* __restrict__ xsbuf, const bf16* __restrict__ zbuf,
                 const float* __restrict__ xp,
                 const float* __restrict__ dt_w, const float* __restrict__ dt_b,
                 const float* __restrict__ A_log, const float* __restrict__ Dvec) {
  __shared__ float sxpT[NXP * PS];               // [j][l] transposed xp
  __shared__ float sdt[4 * PS];                  // delta
  __shared__ float sg[4 * PS];                   // delta*xs
  __shared__ float sxs[4 * PS];                  // xs
  __shared__ float sz[4 * PS];                   // z
  __shared__ __align__(16) float sys[LC * 4];    // gated output staging
  __shared__ float Wtot[NW][64];                 // per-wave per-lane cs2 sums
  __shared__ float Vtot[NW][64];                 // per-wave per-lane S sums
  const int tid = threadIdx.x;
  const int wave = tid >> 6, lane = tid & 63;
  const int s = lane & 15, dl = lane >> 4;
  const int d0 = blockIdx.x * 4;
  const int base = wave * SPW;
  const float As2 = -expf(A_log[s]) * LOG2E;
  const float Dd = Dvec[d0 + dl];
  float dtw[4], dtb[4];
#pragma unroll
  for (int c = 0; c < 4; ++c) {
    dtw[c] = dt_w[d0 + c];
    dtb[c] = dt_b[d0 + c];
  }
  float cs2_carry = 0.f, S_carry = 0.f;
  for (int l0 = 0; l0 < L_SEQ; l0 += LC) {
    // stage xp: coalesced global read, transposed LDS write
    for (int idx = tid; idx < NXP * LC; idx += 1024) {
      int l = idx / NXP, j = idx - l * NXP;
      sxpT[j * PS + l] = xp[(size_t)l0 * NXP + idx];
    }
    // stage xs/z (column gather, 16 waves overlap the latency)
    for (int i = tid; i < LC; i += 1024) {
      float4 xv4 = ld4(xsbuf + (size_t)(l0 + i) * DI + d0);
      float4 zv4 = ld4(zbuf + (size_t)(l0 + i) * DI + d0);
      sxs[0 * PS + i] = xv4.x; sxs[1 * PS + i] = xv4.y;
      sxs[2 * PS + i] = xv4.z; sxs[3 * PS + i] = xv4.w;
      sz[0 * PS + i] = zv4.x; sz[1 * PS + i] = zv4.y;
      sz[2 * PS + i] = zv4.z; sz[3 * PS + i] = zv4.w;
    }
    __syncthreads();
    // delta & g
    for (int i = tid; i < LC; i += 1024) {
      float x0 = sxpT[i];  // j=0 row
#pragma unroll
      for (int c = 0; c < 4; ++c) {
        float a = fmaf(x0, dtw[c], dtb[c]);
        float dt = __log2f(1.f + fexp2(a * LOG2E)) * LN2;
        sdt[c * PS + i] = dt;
        sg[c * PS + i] = dt * sxs[c * PS + i];
      }
    }
    __syncthreads();
    // Pass A: per-wave W totals (u2 cached in registers)
    float u2[SPW];
    float Wl = 0.f;
#pragma unroll
    for (int k = 0; k < SPW; ++k) {
      u2[k] = sdt[dl * PS + base + k] * As2;
      Wl += fmaxf(u2[k], LOG2EPS);
    }
    Wtot[wave][lane] = Wl;
    __syncthreads();
    float O = cs2_carry, Wall = 0.f;
    for (int w = 0; w < NW; ++w) {
      float t = Wtot[w][lane];
      if (w < wave) O += t;
      Wall += t;
    }
    // Pass B: per-wave V totals
    float cs2 = O;
    float rcpA = frcp(fmaxf(fexp2(cs2), EPS));
    float Vl = 0.f;
#pragma unroll
    for (int k = 0; k < SPW; ++k) {
      float gb = sg[dl * PS + base + k] * sxpT[(1 + s) * PS + base + k];
      Vl = fmaf(gb, rcpA, Vl);
      cs2 += fmaxf(u2[k], LOG2EPS);
      rcpA = frcp(fmaxf(fexp2(cs2), EPS));
    }
    Vtot[wave][lane] = Vl;
    __syncthreads();
    float SO = S_carry, Vall = 0.f;
    for (int w = 0; w < NW; ++w) {
      float t = Vtot[w][lane];
      if (w < wave) SO += t;
      Vall += t;
    }
    // Pass C: h, contrib, butterfly, gate
    cs2 = O;
    float S = SO;
    float acum_prev = fexp2(cs2);
#pragma unroll
    for (int k = 0; k < SPW; ++k) {
      float gb = sg[dl * PS + base + k] * sxpT[(1 + s) * PS + base + k];
      S = fmaf(gb, frcp(fmaxf(acum_prev, EPS)), S);
      cs2 += fmaxf(u2[k], LOG2EPS);
      float acum = fexp2(cs2);
      float h = acum * S * frcp(fmaxf(fexp2(u2[k]), EPS));
      float contrib = sxpT[(17 + s) * PS + base + k] * h;
      acum_prev = acum;
      contrib += __shfl_xor(contrib, 8);
      contrib += __shfl_xor(contrib, 4);
      contrib += __shfl_xor(contrib, 2);
      contrib += __shfl_xor(contrib, 1);
      if (s == 0) {
        float xv = sxs[dl * PS + base + k];
        float zv = sz[dl * PS + base + k];
        float yv = contrib + Dd * xv;
        sys[(base + k) * 4 + dl] = yv * zv * frcp(1.f + fexp2(-zv * LOG2E));
      }
    }
    cs2_carry += Wall;
    S_carry += Vall;
    __syncthreads();
    for (int i = tid; i < LC; i += 1024)
      st4(xsbuf + (size_t)(l0 + i) * DI + d0, *(const float4*)&sys[i * 4]);
    __syncthreads();
  }
}

extern "C" void kernel_launch(void* const* d_in, const int* in_sizes, int n_in,
                              void* d_out, int out_size, void* d_ws, size_t ws_size,
                              hipStream_t stream) {
  const float* x       = (const float*)d_in[0];
  const float* W_in    = (const float*)d_in[1];
  const float* conv_w  = (const float*)d_in[2];
  const float* conv_b  = (const float*)d_in[3];
  const float* W_xproj = (const float*)d_in[4];
  const float* dt_w    = (const float*)d_in[5];
  const float* dt_b    = (const float*)d_in[6];
  const float* A_log   = (const float*)d_in[7];
  const float* Dvec    = (const float*)d_in[8];
  const float* W_out   = (const float*)d_in[9];
  float* out = (float*)d_out;

  char* ws = (char*)d_ws;
  const size_t MB = 1024 * 1024;
  bf16* buf0  = (bf16*)(ws);                // [2048][1024]
  bf16* buf1  = (bf16*)(ws + 4 * MB);       // [2048][1024]
  bf16* xbf   = (bf16*)(ws + 8 * MB);       // [2048][512]
  bf16* WinT  = (bf16*)(ws + 10 * MB);      // [2048][512]
  bf16* WoutT = (bf16*)(ws + 12 * MB);      // [512][1024]
  float* xp   = (float*)(ws + 13 * MB);     // [2048][33]

  // 0) casts
  cast_kernel<<<(L_SEQ * DM / 4) / 256, 256, 0, stream>>>(x, xbf);
  transpose_cast_kernel<<<dim3(2 * DI / 32, DM / 32), 256, 0, stream>>>(
      W_in, WinT, DM, 2 * DI);
  transpose_cast_kernel<<<dim3(DM / 32, DI / 32), 256, 0, stream>>>(
      W_out, WoutT, DI, DM);
  // 1a) buf0 = x @ W_in[:, 0:1024]  (x-half)
  gemm_bt_mfma<bf16><<<dim3(DI / 64, L_SEQ / 64), 256, 0, stream>>>(
      xbf, WinT, buf0, L_SEQ, DI, DM, DI);
  // 2) conv + silu -> buf1 (xs)
  conv_silu_kernel<bf16><<<L_SEQ * DI / 256, 256, 0, stream>>>(buf0, conv_w, conv_b, buf1);
  // 3) xp = xs @ W_xproj
  xproj_kernel<bf16><<<L_SEQ, 64, 0, stream>>>(buf1, W_xproj, xp);
  // 1b) buf0 = x @ W_in[:, 1024:2048]  (z-half)
  gemm_bt_mfma<bf16><<<dim3(DI / 64, L_SEQ / 64), 256, 0, stream>>>(
      xbf, WinT + (size_t)DI * DM, buf0, L_SEQ, DI, DM, DI);
  // 4) scan + gate -> buf1 in place (chunk-parallel, 16 waves/block)
  scan_kernel<<<DI / 4, 1024, 0, stream>>>(buf1, buf0, xp, dt_w, dt_b, A_log, Dvec);
  // 5) out = ys @ W_out  (fp32 store)
  gemm_bt_mfma<float><<<dim3(DM / 64, L_SEQ / 64), 256, 0, stream>>>(
      buf1, WoutT, out, L_SEQ, DM, DI, DM);
}

// Round 12
// 278.099 us; speedup vs baseline: 3.8973x; 1.0001x over previous
//
#include <hip/hip_runtime.h>
#include <hip/hip_bf16.h>

// SelectiveSSM: B=1, L=2048, D_MODEL=512, D_INNER=1024, D_STATE=16, D_CONV=4
// ESTABLISHED: inputs fp32, d_out fp32, ws >= 17.05MB. R11: 278us; scan 112us
// with 247MB HBM traffic (column access of row-major bufs: 8B used per 64B
// line x 8 XCD-split blocks per line + partial-line RMW writes).
// R12: layout fix. xs transposed to xsT[d][l] (bf16); scan reads/writes
// contiguous rows, writes un-gated yT in place; new fused gate+transpose
// kernel (yT + z -> gated ys[l][d]) feeds GEMM2. No z transpose needed.
// ws (13.3MB): buf0 4@0 | buf1 4@4 | xbf 2@8+WinT 2@10 (dead after GEMM1b,
// overlaid by xsT 4@8) | WoutT 1@12 | xp 0.26@13.

#define L_SEQ 2048
#define DM 512
#define DI 1024
#define DS 16
#define NXP 33
#define EPS 1e-10f
#define LOG2E 1.44269504088896340736f
#define LN2 0.69314718055994530942f
#define LOG2EPS -33.219280948873623478f  // log2(1e-10)

typedef __hip_bfloat16 bf16;
typedef __attribute__((ext_vector_type(8))) short bf16x8v;
typedef __attribute__((ext_vector_type(4))) float f32x4v;

__device__ __forceinline__ float ldf(const float* p) { return *p; }
__device__ __forceinline__ float ldf(const bf16* p) { return __bfloat162float(*p); }

struct alignas(8) bf16x4 { bf16 x, y, z, w; };

__device__ __forceinline__ float4 ld4(const float* p) { return *(const float4*)p; }
__device__ __forceinline__ float4 ld4(const bf16* p) {
  bf16x4 v = *(const bf16x4*)p;
  return make_float4(__bfloat162float(v.x), __bfloat162float(v.y),
                     __bfloat162float(v.z), __bfloat162float(v.w));
}
__device__ __forceinline__ void st4(float* p, float4 v) { *(float4*)p = v; }
__device__ __forceinline__ void st4(bf16* p, float4 v) {
  bf16x4 o;
  o.x = __float2bfloat16(v.x); o.y = __float2bfloat16(v.y);
  o.z = __float2bfloat16(v.z); o.w = __float2bfloat16(v.w);
  *(bf16x4*)p = o;
}
__device__ __forceinline__ void st1(float* p, float v) { *p = v; }
__device__ __forceinline__ void st1(bf16* p, float v) { *p = __float2bfloat16(v); }

__device__ __forceinline__ float fexp2(float x) { return __builtin_amdgcn_exp2f(x); }
__device__ __forceinline__ float frcp(float x) { return __builtin_amdgcn_rcpf(x); }

// ---------- pre-pass casts ----------

__global__ __launch_bounds__(256)
void cast_kernel(const float* __restrict__ src, bf16* __restrict__ dst) {
  size_t i = (size_t)(blockIdx.x * 256 + threadIdx.x) * 4;
  st4(dst + i, *(const float4*)(src + i));
}

// W[R][C] fp32 -> WT[C][R] bf16, 32x32 LDS tiles. grid (C/32, R/32), 256 thr.
__global__ __launch_bounds__(256)
void transpose_cast_kernel(const float* __restrict__ W, bf16* __restrict__ WT,
                           int R, int C) {
  __shared__ float tile[32][33];
  int c0 = blockIdx.x * 32, r0 = blockIdx.y * 32;
  int tx = threadIdx.x & 31, ty = threadIdx.x >> 5;
#pragma unroll
  for (int i = 0; i < 4; ++i) {
    int rr = ty + i * 8;
    tile[rr][tx] = W[(size_t)(r0 + rr) * C + c0 + tx];
  }
  __syncthreads();
#pragma unroll
  for (int i = 0; i < 4; ++i) {
    int cc = ty + i * 8;
    WT[(size_t)(c0 + cc) * R + r0 + tx] = __float2bfloat16(tile[tx][cc]);
  }
}

// bf16 [R][C] -> [C][R], 64x64 tiles, 256 threads, 16B global accesses.
__global__ __launch_bounds__(256)
void transpose_bf16(const bf16* __restrict__ in, bf16* __restrict__ out,
                    int R, int C) {
  __shared__ bf16 tile[64][72];
  int r0 = blockIdx.y * 64, c0 = blockIdx.x * 64;
#pragma unroll
  for (int it = 0; it < 2; ++it) {
    int slot = threadIdx.x + it * 256;
    int rr = slot >> 3, seg = slot & 7;
    *(uint4*)&tile[rr][seg * 8] = *(const uint4*)(in + (size_t)(r0 + rr) * C + c0 + seg * 8);
  }
  __syncthreads();
#pragma unroll
  for (int it = 0; it < 2; ++it) {
    int slot = threadIdx.x + it * 256;
    int cc = slot >> 3, seg = slot & 7;
    bf16 tmp[8];
#pragma unroll
    for (int j = 0; j < 8; ++j) tmp[j] = tile[seg * 8 + j][cc];
    *(uint4*)(out + (size_t)(c0 + cc) * R + r0 + seg * 8) = *(uint4*)tmp;
  }
}

// ys[l][d] = yT[d][l] * silu(z[l][d]).  yT: [DI][L], z: buf0 [L][DI].
__global__ __launch_bounds__(256)
void gate_transpose_kernel(const bf16* __restrict__ yT, const bf16* __restrict__ zbuf,
                           bf16* __restrict__ ys) {
  __shared__ bf16 tile[64][72];
  int d0 = blockIdx.y * 64, l0 = blockIdx.x * 64;
#pragma unroll
  for (int it = 0; it < 2; ++it) {
    int slot = threadIdx.x + it * 256;
    int dd = slot >> 3, seg = slot & 7;
    *(uint4*)&tile[dd][seg * 8] = *(const uint4*)(yT + (size_t)(d0 + dd) * L_SEQ + l0 + seg * 8);
  }
  __syncthreads();
#pragma unroll
  for (int it = 0; it < 2; ++it) {
    int slot = threadIdx.x + it * 256;
    int ll = slot >> 3, seg = slot & 7;
    const bf16* zp = zbuf + (size_t)(l0 + ll) * DI + d0 + seg * 8;
    bf16 zt[8];
    *(uint4*)zt = *(const uint4*)zp;
    bf16 o[8];
#pragma unroll
    for (int j = 0; j < 8; ++j) {
      float yv = __bfloat162float(tile[seg * 8 + j][ll]);
      float zv = __bfloat162float(zt[j]);
      o[j] = __float2bfloat16(yv * zv * frcp(1.f + fexp2(-zv * LOG2E)));
    }
    *(uint4*)(ys + (size_t)(l0 + ll) * DI + d0 + seg * 8) = *(uint4*)o;
  }
}

// ---------- MFMA GEMM: C[M][N] = A[M][K] @ BT[N][K]^T (bf16 in, TC out) ----
template <typename TC>
__global__ __launch_bounds__(256)
void gemm_bt_mfma(const bf16* __restrict__ A, const bf16* __restrict__ BT,
                  TC* __restrict__ C, int M, int N, int K, int ldc) {
  __shared__ __align__(16) bf16 As[64 * 40];
  __shared__ __align__(16) bf16 Bs[64 * 40];
  const int tid = threadIdx.x;
  const int wave = tid >> 6, lane = tid & 63;
  const int q = lane >> 4, r = lane & 15;
  const int row0 = blockIdx.y * 64, col0 = blockIdx.x * 64;
  const int srow = tid >> 2, sseg = tid & 3;
  f32x4v acc[4] = {};
  for (int k0 = 0; k0 < K; k0 += 32) {
    uint4 av = *(const uint4*)(A + (size_t)(row0 + srow) * K + k0 + sseg * 8);
    uint4 bv = *(const uint4*)(BT + (size_t)(col0 + srow) * K + k0 + sseg * 8);
    *(uint4*)&As[srow * 40 + sseg * 8] = av;
    *(uint4*)&Bs[srow * 40 + sseg * 8] = bv;
    __syncthreads();
    bf16x8v a = *(const bf16x8v*)&As[(wave * 16 + r) * 40 + q * 8];
#pragma unroll
    for (int j = 0; j < 4; ++j) {
      bf16x8v b = *(const bf16x8v*)&Bs[(j * 16 + r) * 40 + q * 8];
      acc[j] = __builtin_amdgcn_mfma_f32_16x16x32_bf16(a, b, acc[j], 0, 0, 0);
    }
    __syncthreads();
  }
#pragma unroll
  for (int j = 0; j < 4; ++j)
#pragma unroll
    for (int reg = 0; reg < 4; ++reg) {
      int m = row0 + wave * 16 + q * 4 + reg;
      int n = col0 + j * 16 + r;
      st1(C + (size_t)m * ldc + n, acc[j][reg]);
    }
}

// ---------- conv / xproj ----------

template <typename T>
__global__ __launch_bounds__(256)
void conv_silu_kernel(const T* __restrict__ xpre, const float* __restrict__ conv_w,
                      const float* __restrict__ conv_b, T* __restrict__ xs) {
  int idx = blockIdx.x * 256 + threadIdx.x;  // l*1024 + d
  int d = idx & (DI - 1);
  int l = idx >> 10;
  float acc = conv_b[d];
#pragma unroll
  for (int k = 0; k < 4; ++k) {
    int ls = l + k - 3;
    if (ls >= 0) acc = fmaf(ldf(xpre + (size_t)ls * DI + d), conv_w[d * 4 + k], acc);
  }
  st1(xs + idx, acc / (1.f + __expf(-acc)));
}

template <typename T>
__global__ __launch_bounds__(64)
void xproj_kernel(const T* __restrict__ xs, const float* __restrict__ W_xproj,
                  float* __restrict__ xp) {
  __shared__ float row[DI];
  int l = blockIdx.x;
  for (int i = threadIdx.x; i < DI; i += 64) row[i] = ldf(xs + (size_t)l * DI + i);
  __syncthreads();
  int j = threadIdx.x;
  if (j < NXP) {
    float acc = 0.f;
#pragma unroll 8
    for (int i = 0; i < DI; ++i)
      acc = fmaf(row[i], W_xproj[i * NXP + j], acc);
    xp[l * NXP + j] = acc;
  }
}

// ---------- chunk-parallel scan on transposed layout ----------
// 16 waves; wave owns SPW=32 steps of the LC=512 chunk. xsT rows are
// contiguous: staging fully coalesced. Writes un-gated yT in place.
#define LC 512
#define NW 16
#define SPW 32
#define PSX 513  // sxpT row stride
#define LCP 516  // sdt/sg/sxs/sys row stride

__global__ __launch_bounds__(1024)
void scan_kernel(bf16* __restrict__ xsT, const float* __restrict__ xp,
                 const float* __restrict__ dt_w, const float* __restrict__ dt_b,
                 const float* __restrict__ A_log, const float* __restrict__ Dvec) {
  __shared__ float sxpT[NXP * PSX];
  __shared__ float sdt[4 * LCP], sg[4 * LCP], sxs[4 * LCP];
  __shared__ float sys[4 * LCP];
  __shared__ float Wtot[NW][64], Vtot[NW][64];
  const int tid = threadIdx.x;
  const int wave = tid >> 6, lane = tid & 63;
  const int s = lane & 15, dl = lane >> 4;
  const int d0 = blockIdx.x * 4;
  const int base = wave * SPW;
  const float As2 = -expf(A_log[s]) * LOG2E;
  const float Dd = Dvec[d0 + dl];
  float dtw[4], dtb[4];
#pragma unroll
  for (int c = 0; c < 4; ++c) {
    dtw[c] = dt_w[d0 + c];
    dtb[c] = dt_b[d0 + c];
  }
  float cs2_carry = 0.f, S_carry = 0.f;
  for (int l0 = 0; l0 < L_SEQ; l0 += LC) {
    // stage xp (coalesced global read, transposed LDS write)
    for (int idx = tid; idx < NXP * LC; idx += 1024) {
      int l = idx / NXP, j = idx - l * NXP;
      sxpT[j * PSX + l] = xp[(size_t)l0 * NXP + idx];
    }
    // stage xs rows (4 x 512 bf16, contiguous)
    for (int slot = tid; slot < 4 * (LC / 8); slot += 1024) {
      int c = slot >> 6, seg = slot & 63;
      bf16 tmp[8];
      *(uint4*)tmp = *(const uint4*)(xsT + (size_t)(d0 + c) * L_SEQ + l0 + seg * 8);
#pragma unroll
      for (int j = 0; j < 8; ++j) sxs[c * LCP + seg * 8 + j] = __bfloat162float(tmp[j]);
    }
    __syncthreads();
    // delta & g
    for (int i = tid; i < LC; i += 1024) {
      float x0 = sxpT[i];  // j=0 row
#pragma unroll
      for (int c = 0; c < 4; ++c) {
        float a = fmaf(x0, dtw[c], dtb[c]);
        float dt = __log2f(1.f + fexp2(a * LOG2E)) * LN2;
        sdt[c * LCP + i] = dt;
        sg[c * LCP + i] = dt * sxs[c * LCP + i];
      }
    }
    __syncthreads();
    // Pass A: per-wave W totals
    float u2[SPW];
    float Wl = 0.f;
#pragma unroll
    for (int k = 0; k < SPW; ++k) {
      u2[k] = sdt[dl * LCP + base + k] * As2;
      Wl += fmaxf(u2[k], LOG2EPS);
    }
    Wtot[wave][lane] = Wl;
    __syncthreads();
    float O = cs2_carry, Wall = 0.f;
    for (int w = 0; w < NW; ++w) {
      float t = Wtot[w][lane];
      if (w < wave) O += t;
      Wall += t;
    }
    // Pass B: per-wave V totals
    float cs2 = O;
    float rcpA = frcp(fmaxf(fexp2(cs2), EPS));
    float Vl = 0.f;
#pragma unroll
    for (int k = 0; k < SPW; ++k) {
      float gb = sg[dl * LCP + base + k] * sxpT[(1 + s) * PSX + base + k];
      Vl = fmaf(gb, rcpA, Vl);
      cs2 += fmaxf(u2[k], LOG2EPS);
      rcpA = frcp(fmaxf(fexp2(cs2), EPS));
    }
    Vtot[wave][lane] = Vl;
    __syncthreads();
    float SO = S_carry, Vall = 0.f;
    for (int w = 0; w < NW; ++w) {
      float t = Vtot[w][lane];
      if (w < wave) SO += t;
      Vall += t;
    }
    // Pass C: h, contrib, butterfly; un-gated y into sys
    cs2 = O;
    float S = SO;
    float acum_prev = fexp2(cs2);
#pragma unroll
    for (int k = 0; k < SPW; ++k) {
      float gb = sg[dl * LCP + base + k] * sxpT[(1 + s) * PSX + base + k];
      S = fmaf(gb, frcp(fmaxf(acum_prev, EPS)), S);
      cs2 += fmaxf(u2[k], LOG2EPS);
      float acum = fexp2(cs2);
      float h = acum * S * frcp(fmaxf(fexp2(u2[k]), EPS));
      float contrib = sxpT[(17 + s) * PSX + base + k] * h;
      acum_prev = acum;
      contrib += __shfl_xor(contrib, 8);
      contrib += __shfl_xor(contrib, 4);
      contrib += __shfl_xor(contrib, 2);
      contrib += __shfl_xor(contrib, 1);
      if (s == 0)
        sys[dl * LCP + base + k] = contrib + Dd * sxs[dl * LCP + base + k];
    }
    cs2_carry += Wall;
    S_carry += Vall;
    __syncthreads();
    // store yT rows (bf16, in place over xsT)
    for (int slot = tid; slot < 4 * (LC / 8); slot += 1024) {
      int c = slot >> 6, seg = slot & 63;
      bf16 tmp[8];
#pragma unroll
      for (int j = 0; j < 8; ++j) tmp[j] = __float2bfloat16(sys[c * LCP + seg * 8 + j]);
      *(uint4*)(xsT + (size_t)(d0 + c) * L_SEQ + l0 + seg * 8) = *(uint4*)tmp;
    }
    __syncthreads();
  }
}

extern "C" void kernel_launch(void* const* d_in, const int* in_sizes, int n_in,
                              void* d_out, int out_size, void* d_ws, size_t ws_size,
                              hipStream_t stream) {
  const float* x       = (const float*)d_in[0];
  const float* W_in    = (const float*)d_in[1];
  const float* conv_w  = (const float*)d_in[2];
  const float* conv_b  = (const float*)d_in[3];
  const float* W_xproj = (const float*)d_in[4];
  const float* dt_w    = (const float*)d_in[5];
  const float* dt_b    = (const float*)d_in[6];
  const float* A_log   = (const float*)d_in[7];
  const float* Dvec    = (const float*)d_in[8];
  const float* W_out   = (const float*)d_in[9];
  float* out = (float*)d_out;

  char* ws = (char*)d_ws;
  const size_t MB = 1024 * 1024;
  bf16* buf0  = (bf16*)(ws);            // [2048][1024] xz x-half, then z
  bf16* buf1  = (bf16*)(ws + 4 * MB);   // [2048][1024] xs, later gated ys
  bf16* xbf   = (bf16*)(ws + 8 * MB);   // [2048][512]  (dead after GEMM1b)
  bf16* WinT  = (bf16*)(ws + 10 * MB);  // [2048][512]  (dead after GEMM1b)
  bf16* xsT   = (bf16*)(ws + 8 * MB);   // [1024][2048] overlays xbf+WinT
  bf16* WoutT = (bf16*)(ws + 12 * MB);  // [512][1024]
  float* xp   = (float*)(ws + 13 * MB); // [2048][33]

  // 0) casts
  cast_kernel<<<(L_SEQ * DM / 4) / 256, 256, 0, stream>>>(x, xbf);
  transpose_cast_kernel<<<dim3(2 * DI / 32, DM / 32), 256, 0, stream>>>(
      W_in, WinT, DM, 2 * DI);
  transpose_cast_kernel<<<dim3(DM / 32, DI / 32), 256, 0, stream>>>(
      W_out, WoutT, DI, DM);
  // 1a) buf0 = x @ W_in[:, 0:1024]  (x-half)
  gemm_bt_mfma<bf16><<<dim3(DI / 64, L_SEQ / 64), 256, 0, stream>>>(
      xbf, WinT, buf0, L_SEQ, DI, DM, DI);
  // 2) conv + silu -> buf1 (xs, [l][d])
  conv_silu_kernel<bf16><<<L_SEQ * DI / 256, 256, 0, stream>>>(buf0, conv_w, conv_b, buf1);
  // 3) xp = xs @ W_xproj
  xproj_kernel<bf16><<<L_SEQ, 64, 0, stream>>>(buf1, W_xproj, xp);
  // 1b) buf0 = x @ W_in[:, 1024:2048]  (z; x-pre dead)
  gemm_bt_mfma<bf16><<<dim3(DI / 64, L_SEQ / 64), 256, 0, stream>>>(
      xbf, WinT + (size_t)DI * DM, buf0, L_SEQ, DI, DM, DI);
  // 4) xs -> xsT  (xbf/WinT dead now)
  transpose_bf16<<<dim3(DI / 64, L_SEQ / 64), 256, 0, stream>>>(buf1, xsT, L_SEQ, DI);
  // 5) scan: un-gated yT written in place over xsT
  scan_kernel<<<DI / 4, 1024, 0, stream>>>(xsT, xp, dt_w, dt_b, A_log, Dvec);
  // 6) gate + transpose: ys[l][d] = yT * silu(z) -> buf1
  gate_transpose_kernel<<<dim3(L_SEQ / 64, DI / 64), 256, 0, stream>>>(xsT, buf0, buf1);
  // 7) out = ys @ W_out  (fp32 store)
  gemm_bt_mfma<float><<<dim3(DM / 64, L_SEQ / 64), 256, 0, stream>>>(
      buf1, WoutT, out, L_SEQ, DM, DI, DM);
}

// Round 14
// 264.509 us; speedup vs baseline: 4.0976x; 1.0514x over previous
//
#include <hip/hip_runtime.h>
#include <hip/hip_bf16.h>

// SelectiveSSM: B=1, L=2048, D_MODEL=512, D_INNER=1024, D_STATE=16, D_CONV=4
// ESTABLISHED: inputs fp32, d_out fp32, ws >= 17.05MB.
// R14 == R13 with compile fix (__builtin_nontemporal_store needs a native
// ext_vector_type pointer, not HIP's uint4 class).
//  - xproj broadcast elephant (2048 blocks x 135KB W_xproj = 276MB) replaced
//    by MFMA GEMM vs zero-padded bf16 WxT[64][1024] -> xpP[2048][64] fp32 ->
//    compact transpose xpcT[33][2048].
//  - Scan stages xpcT rows coalesced; yT stores nontemporal (WRITE probe).
// ws: buf0 4@0 | buf1 4@4 | xbf 2@8 + WinT 2@10 (dead after GEMM1b; xsT 4@8
// overlays) | WoutT 1@12 | xpP 0.5@13 | xpcT 0.26@13.5 | WxT 0.13@13.8

#define L_SEQ 2048
#define DM 512
#define DI 1024
#define DS 16
#define NXP 33
#define EPS 1e-10f
#define LOG2E 1.44269504088896340736f
#define LN2 0.69314718055994530942f
#define LOG2EPS -33.219280948873623478f  // log2(1e-10)

typedef __hip_bfloat16 bf16;
typedef __attribute__((ext_vector_type(8))) short bf16x8v;
typedef __attribute__((ext_vector_type(4))) float f32x4v;
typedef __attribute__((ext_vector_type(4))) unsigned int u32x4v;  // NT-store safe

__device__ __forceinline__ float ldf(const float* p) { return *p; }
__device__ __forceinline__ float ldf(const bf16* p) { return __bfloat162float(*p); }

struct alignas(8) bf16x4 { bf16 x, y, z, w; };

__device__ __forceinline__ float4 ld4(const float* p) { return *(const float4*)p; }
__device__ __forceinline__ float4 ld4(const bf16* p) {
  bf16x4 v = *(const bf16x4*)p;
  return make_float4(__bfloat162float(v.x), __bfloat162float(v.y),
                     __bfloat162float(v.z), __bfloat162float(v.w));
}
__device__ __forceinline__ void st4(float* p, float4 v) { *(float4*)p = v; }
__device__ __forceinline__ void st4(bf16* p, float4 v) {
  bf16x4 o;
  o.x = __float2bfloat16(v.x); o.y = __float2bfloat16(v.y);
  o.z = __float2bfloat16(v.z); o.w = __float2bfloat16(v.w);
  *(bf16x4*)p = o;
}
__device__ __forceinline__ void st1(float* p, float v) { *p = v; }
__device__ __forceinline__ void st1(bf16* p, float v) { *p = __float2bfloat16(v); }

__device__ __forceinline__ float fexp2(float x) { return __builtin_amdgcn_exp2f(x); }
__device__ __forceinline__ float frcp(float x) { return __builtin_amdgcn_rcpf(x); }

// ---------- pre-pass casts ----------

__global__ __launch_bounds__(256)
void cast_kernel(const float* __restrict__ src, bf16* __restrict__ dst) {
  size_t i = (size_t)(blockIdx.x * 256 + threadIdx.x) * 4;
  st4(dst + i, *(const float4*)(src + i));
}

// W[R][C] fp32 -> WT[C][R] bf16, 32x32 LDS tiles. grid (C/32, R/32), 256 thr.
__global__ __launch_bounds__(256)
void transpose_cast_kernel(const float* __restrict__ W, bf16* __restrict__ WT,
                           int R, int C) {
  __shared__ float tile[32][33];
  int c0 = blockIdx.x * 32, r0 = blockIdx.y * 32;
  int tx = threadIdx.x & 31, ty = threadIdx.x >> 5;
#pragma unroll
  for (int i = 0; i < 4; ++i) {
    int rr = ty + i * 8;
    tile[rr][tx] = W[(size_t)(r0 + rr) * C + c0 + tx];
  }
  __syncthreads();
#pragma unroll
  for (int i = 0; i < 4; ++i) {
    int cc = ty + i * 8;
    WT[(size_t)(c0 + cc) * R + r0 + tx] = __float2bfloat16(tile[tx][cc]);
  }
}

// W_xproj [1024][33] fp32 -> WxT [64][1024] bf16, rows >=33 zeroed.
__global__ __launch_bounds__(256)
void wxproj_pad_kernel(const float* __restrict__ W, bf16* __restrict__ WxT) {
  int idx = blockIdx.x * 256 + threadIdx.x;  // j*1024 + i
  int j = idx >> 10, i = idx & 1023;
  float v = (j < NXP) ? W[i * NXP + j] : 0.f;
  WxT[idx] = __float2bfloat16(v);
}

// xpP [2048][64] fp32 -> xpcT [33][2048] fp32 (transpose-compact).
__global__ __launch_bounds__(256)
void xp_compact_kernel(const float* __restrict__ xpP, float* __restrict__ xpcT) {
  __shared__ float tile[64][65];
  int l0 = blockIdx.x * 64;
#pragma unroll
  for (int it = 0; it < 16; ++it) {
    int idx = it * 256 + threadIdx.x;
    int rr = idx >> 6, cc = idx & 63;
    tile[rr][cc] = xpP[(size_t)(l0 + rr) * 64 + cc];
  }
  __syncthreads();
#pragma unroll
  for (int it = 0; it < 9; ++it) {
    int idx = it * 256 + threadIdx.x;
    if (idx < NXP * 64) {
      int j = idx >> 6, ll = idx & 63;
      xpcT[(size_t)j * L_SEQ + l0 + ll] = tile[ll][j];
    }
  }
}

// bf16 [R][C] -> [C][R], 64x64 tiles, 256 threads, 16B global accesses.
__global__ __launch_bounds__(256)
void transpose_bf16(const bf16* __restrict__ in, bf16* __restrict__ out,
                    int R, int C) {
  __shared__ bf16 tile[64][72];
  int r0 = blockIdx.y * 64, c0 = blockIdx.x * 64;
#pragma unroll
  for (int it = 0; it < 2; ++it) {
    int slot = threadIdx.x + it * 256;
    int rr = slot >> 3, seg = slot & 7;
    *(uint4*)&tile[rr][seg * 8] = *(const uint4*)(in + (size_t)(r0 + rr) * C + c0 + seg * 8);
  }
  __syncthreads();
#pragma unroll
  for (int it = 0; it < 2; ++it) {
    int slot = threadIdx.x + it * 256;
    int cc = slot >> 3, seg = slot & 7;
    bf16 tmp[8];
#pragma unroll
    for (int j = 0; j < 8; ++j) tmp[j] = tile[seg * 8 + j][cc];
    *(uint4*)(out + (size_t)(c0 + cc) * R + r0 + seg * 8) = *(uint4*)tmp;
  }
}

// ys[l][d] = yT[d][l] * silu(z[l][d]).
__global__ __launch_bounds__(256)
void gate_transpose_kernel(const bf16* __restrict__ yT, const bf16* __restrict__ zbuf,
                           bf16* __restrict__ ys) {
  __shared__ bf16 tile[64][72];
  int d0 = blockIdx.y * 64, l0 = blockIdx.x * 64;
#pragma unroll
  for (int it = 0; it < 2; ++it) {
    int slot = threadIdx.x + it * 256;
    int dd = slot >> 3, seg = slot & 7;
    *(uint4*)&tile[dd][seg * 8] = *(const uint4*)(yT + (size_t)(d0 + dd) * L_SEQ + l0 + seg * 8);
  }
  __syncthreads();
#pragma unroll
  for (int it = 0; it < 2; ++it) {
    int slot = threadIdx.x + it * 256;
    int ll = slot >> 3, seg = slot & 7;
    bf16 zt[8];
    *(uint4*)zt = *(const uint4*)(zbuf + (size_t)(l0 + ll) * DI + d0 + seg * 8);
    bf16 o[8];
#pragma unroll
    for (int j = 0; j < 8; ++j) {
      float yv = __bfloat162float(tile[seg * 8 + j][ll]);
      float zv = __bfloat162float(zt[j]);
      o[j] = __float2bfloat16(yv * zv * frcp(1.f + fexp2(-zv * LOG2E)));
    }
    *(uint4*)(ys + (size_t)(l0 + ll) * DI + d0 + seg * 8) = *(uint4*)o;
  }
}

// ---------- MFMA GEMM: C[M][N] = A[M][K] @ BT[N][K]^T (bf16 in, TC out) ----
template <typename TC>
__global__ __launch_bounds__(256)
void gemm_bt_mfma(const bf16* __restrict__ A, const bf16* __restrict__ BT,
                  TC* __restrict__ C, int M, int N, int K, int ldc) {
  __shared__ __align__(16) bf16 As[64 * 40];
  __shared__ __align__(16) bf16 Bs[64 * 40];
  const int tid = threadIdx.x;
  const int wave = tid >> 6, lane = tid & 63;
  const int q = lane >> 4, r = lane & 15;
  const int row0 = blockIdx.y * 64, col0 = blockIdx.x * 64;
  const int srow = tid >> 2, sseg = tid & 3;
  f32x4v acc[4] = {};
  for (int k0 = 0; k0 < K; k0 += 32) {
    uint4 av = *(const uint4*)(A + (size_t)(row0 + srow) * K + k0 + sseg * 8);
    uint4 bv = *(const uint4*)(BT + (size_t)(col0 + srow) * K + k0 + sseg * 8);
    *(uint4*)&As[srow * 40 + sseg * 8] = av;
    *(uint4*)&Bs[srow * 40 + sseg * 8] = bv;
    __syncthreads();
    bf16x8v a = *(const bf16x8v*)&As[(wave * 16 + r) * 40 + q * 8];
#pragma unroll
    for (int j = 0; j < 4; ++j) {
      bf16x8v b = *(const bf16x8v*)&Bs[(j * 16 + r) * 40 + q * 8];
      acc[j] = __builtin_amdgcn_mfma_f32_16x16x32_bf16(a, b, acc[j], 0, 0, 0);
    }
    __syncthreads();
  }
#pragma unroll
  for (int j = 0; j < 4; ++j)
#pragma unroll
    for (int reg = 0; reg < 4; ++reg) {
      int m = row0 + wave * 16 + q * 4 + reg;
      int n = col0 + j * 16 + r;
      st1(C + (size_t)m * ldc + n, acc[j][reg]);
    }
}

// ---------- conv ----------

template <typename T>
__global__ __launch_bounds__(256)
void conv_silu_kernel(const T* __restrict__ xpre, const float* __restrict__ conv_w,
                      const float* __restrict__ conv_b, T* __restrict__ xs) {
  int idx = blockIdx.x * 256 + threadIdx.x;  // l*1024 + d
  int d = idx & (DI - 1);
  int l = idx >> 10;
  float acc = conv_b[d];
#pragma unroll
  for (int k = 0; k < 4; ++k) {
    int ls = l + k - 3;
    if (ls >= 0) acc = fmaf(ldf(xpre + (size_t)ls * DI + d), conv_w[d * 4 + k], acc);
  }
  st1(xs + idx, acc / (1.f + __expf(-acc)));
}

// ---------- chunk-parallel scan (transposed layout, xpcT rows) ----------
#define LC 512
#define NW 16
#define SPW 32
#define PSX 513
#define LCP 516

__global__ __launch_bounds__(1024)
void scan_kernel(bf16* __restrict__ xsT, const float* __restrict__ xpcT,
                 const float* __restrict__ dt_w, const float* __restrict__ dt_b,
                 const float* __restrict__ A_log, const float* __restrict__ Dvec) {
  __shared__ float sxpT[NXP * PSX];
  __shared__ float sdt[4 * LCP], sg[4 * LCP], sxs[4 * LCP];
  __shared__ float sys[4 * LCP];
  __shared__ float Wtot[NW][64], Vtot[NW][64];
  const int tid = threadIdx.x;
  const int wave = tid >> 6, lane = tid & 63;
  const int s = lane & 15, dl = lane >> 4;
  const int d0 = blockIdx.x * 4;
  const int base = wave * SPW;
  const float As2 = -expf(A_log[s]) * LOG2E;
  const float Dd = Dvec[d0 + dl];
  float dtw[4], dtb[4];
#pragma unroll
  for (int c = 0; c < 4; ++c) {
    dtw[c] = dt_w[d0 + c];
    dtb[c] = dt_b[d0 + c];
  }
  float cs2_carry = 0.f, S_carry = 0.f;
  for (int l0 = 0; l0 < L_SEQ; l0 += LC) {
    // stage xpcT rows (coalesced; row j -> sxpT[j][*])
    for (int idx = tid; idx < NXP * LC; idx += 1024) {
      int j = idx >> 9, l = idx & (LC - 1);
      sxpT[j * PSX + l] = xpcT[(size_t)j * L_SEQ + l0 + l];
    }
    // stage xs rows (4 x 512 bf16, contiguous)
    for (int slot = tid; slot < 4 * (LC / 8); slot += 1024) {
      int c = slot >> 6, seg = slot & 63;
      bf16 tmp[8];
      *(uint4*)tmp = *(const uint4*)(xsT + (size_t)(d0 + c) * L_SEQ + l0 + seg * 8);
#pragma unroll
      for (int j = 0; j < 8; ++j) sxs[c * LCP + seg * 8 + j] = __bfloat162float(tmp[j]);
    }
    __syncthreads();
    // delta & g
    for (int i = tid; i < LC; i += 1024) {
      float x0 = sxpT[i];  // j=0 row
#pragma unroll
      for (int c = 0; c < 4; ++c) {
        float a = fmaf(x0, dtw[c], dtb[c]);
        float dt = __log2f(1.f + fexp2(a * LOG2E)) * LN2;
        sdt[c * LCP + i] = dt;
        sg[c * LCP + i] = dt * sxs[c * LCP + i];
      }
    }
    __syncthreads();
    // Pass A: per-wave W totals
    float u2[SPW];
    float Wl = 0.f;
#pragma unroll
    for (int k = 0; k < SPW; ++k) {
      u2[k] = sdt[dl * LCP + base + k] * As2;
      Wl += fmaxf(u2[k], LOG2EPS);
    }
    Wtot[wave][lane] = Wl;
    __syncthreads();
    float O = cs2_carry, Wall = 0.f;
    for (int w = 0; w < NW; ++w) {
      float t = Wtot[w][lane];
      if (w < wave) O += t;
      Wall += t;
    }
    // Pass B: per-wave V totals
    float cs2 = O;
    float rcpA = frcp(fmaxf(fexp2(cs2), EPS));
    float Vl = 0.f;
#pragma unroll
    for (int k = 0; k < SPW; ++k) {
      float gb = sg[dl * LCP + base + k] * sxpT[(1 + s) * PSX + base + k];
      Vl = fmaf(gb, rcpA, Vl);
      cs2 += fmaxf(u2[k], LOG2EPS);
      rcpA = frcp(fmaxf(fexp2(cs2), EPS));
    }
    Vtot[wave][lane] = Vl;
    __syncthreads();
    float SO = S_carry, Vall = 0.f;
    for (int w = 0; w < NW; ++w) {
      float t = Vtot[w][lane];
      if (w < wave) SO += t;
      Vall += t;
    }
    // Pass C: h, contrib, butterfly; un-gated y into sys
    cs2 = O;
    float S = SO;
    float acum_prev = fexp2(cs2);
#pragma unroll
    for (int k = 0; k < SPW; ++k) {
      float gb = sg[dl * LCP + base + k] * sxpT[(1 + s) * PSX + base + k];
      S = fmaf(gb, frcp(fmaxf(acum_prev, EPS)), S);
      cs2 += fmaxf(u2[k], LOG2EPS);
      float acum = fexp2(cs2);
      float h = acum * S * frcp(fmaxf(fexp2(u2[k]), EPS));
      float contrib = sxpT[(17 + s) * PSX + base + k] * h;
      acum_prev = acum;
      contrib += __shfl_xor(contrib, 8);
      contrib += __shfl_xor(contrib, 4);
      contrib += __shfl_xor(contrib, 2);
      contrib += __shfl_xor(contrib, 1);
      if (s == 0)
        sys[dl * LCP + base + k] = contrib + Dd * sxs[dl * LCP + base + k];
    }
    cs2_carry += Wall;
    S_carry += Vall;
    __syncthreads();
    // store yT rows (bf16, in place over xsT), nontemporal
    for (int slot = tid; slot < 4 * (LC / 8); slot += 1024) {
      int c = slot >> 6, seg = slot & 63;
      bf16 tmp[8];
#pragma unroll
      for (int j = 0; j < 8; ++j) tmp[j] = __float2bfloat16(sys[c * LCP + seg * 8 + j]);
      u32x4v vv;
      vv.x = ((unsigned int*)tmp)[0]; vv.y = ((unsigned int*)tmp)[1];
      vv.z = ((unsigned int*)tmp)[2]; vv.w = ((unsigned int*)tmp)[3];
      __builtin_nontemporal_store(vv,
          (u32x4v*)(xsT + (size_t)(d0 + c) * L_SEQ + l0 + seg * 8));
    }
    __syncthreads();
  }
}

extern "C" void kernel_launch(void* const* d_in, const int* in_sizes, int n_in,
                              void* d_out, int out_size, void* d_ws, size_t ws_size,
                              hipStream_t stream) {
  const float* x       = (const float*)d_in[0];
  const float* W_in    = (const float*)d_in[1];
  const float* conv_w  = (const float*)d_in[2];
  const float* conv_b  = (const float*)d_in[3];
  const float* W_xproj = (const float*)d_in[4];
  const float* dt_w    = (const float*)d_in[5];
  const float* dt_b    = (const float*)d_in[6];
  const float* A_log   = (const float*)d_in[7];
  const float* Dvec    = (const float*)d_in[8];
  const float* W_out   = (const float*)d_in[9];
  float* out = (float*)d_out;

  char* ws = (char*)d_ws;
  const size_t MB = 1024 * 1024;
  bf16* buf0  = (bf16*)(ws);                   // [2048][1024]
  bf16* buf1  = (bf16*)(ws + 4 * MB);          // [2048][1024]
  bf16* xbf   = (bf16*)(ws + 8 * MB);          // [2048][512] (dead after 1b)
  bf16* WinT  = (bf16*)(ws + 10 * MB);         // [2048][512] (dead after 1b)
  bf16* xsT   = (bf16*)(ws + 8 * MB);          // [1024][2048] overlays
  bf16* WoutT = (bf16*)(ws + 12 * MB);         // [512][1024]
  float* xpP  = (float*)(ws + 13 * MB);        // [2048][64]
  float* xpcT = (float*)(ws + 13 * MB + 512 * 1024);        // [33][2048]
  bf16* WxT   = (bf16*)(ws + 13 * MB + 512 * 1024 + 288 * 1024);  // [64][1024]

  // 0) casts
  cast_kernel<<<(L_SEQ * DM / 4) / 256, 256, 0, stream>>>(x, xbf);
  transpose_cast_kernel<<<dim3(2 * DI / 32, DM / 32), 256, 0, stream>>>(
      W_in, WinT, DM, 2 * DI);
  transpose_cast_kernel<<<dim3(DM / 32, DI / 32), 256, 0, stream>>>(
      W_out, WoutT, DI, DM);
  wxproj_pad_kernel<<<64 * DI / 256, 256, 0, stream>>>(W_xproj, WxT);
  // 1a) buf0 = x @ W_in[:, 0:1024]  (x-half)
  gemm_bt_mfma<bf16><<<dim3(DI / 64, L_SEQ / 64), 256, 0, stream>>>(
      xbf, WinT, buf0, L_SEQ, DI, DM, DI);
  // 2) conv + silu -> buf1 (xs, [l][d])
  conv_silu_kernel<bf16><<<L_SEQ * DI / 256, 256, 0, stream>>>(buf0, conv_w, conv_b, buf1);
  // 3) xpP = xs @ WxT^T  (MFMA, N=64), then compact to xpcT[33][2048]
  gemm_bt_mfma<float><<<dim3(1, L_SEQ / 64), 256, 0, stream>>>(
      buf1, WxT, xpP, L_SEQ, 64, DI, 64);
  xp_compact_kernel<<<L_SEQ / 64, 256, 0, stream>>>(xpP, xpcT);
  // 1b) buf0 = x @ W_in[:, 1024:2048]  (z; x-pre dead)
  gemm_bt_mfma<bf16><<<dim3(DI / 64, L_SEQ / 64), 256, 0, stream>>>(
      xbf, WinT + (size_t)DI * DM, buf0, L_SEQ, DI, DM, DI);
  // 4) xs -> xsT  (xbf/WinT dead now)
  transpose_bf16<<<dim3(DI / 64, L_SEQ / 64), 256, 0, stream>>>(buf1, xsT, L_SEQ, DI);
  // 5) scan: un-gated yT in place over xsT
  scan_kernel<<<DI / 4, 1024, 0, stream>>>(xsT, xpcT, dt_w, dt_b, A_log, Dvec);
  // 6) gate + transpose: ys[l][d] = yT * silu(z) -> buf1
  gate_transpose_kernel<<<dim3(L_SEQ / 64, DI / 64), 256, 0, stream>>>(xsT, buf0, buf1);
  // 7) out = ys @ W_out  (fp32 store)
  gemm_bt_mfma<float><<<dim3(DM / 64, L_SEQ / 64), 256, 0, stream>>>(
      buf1, WoutT, out, L_SEQ, DM, DI, DM);
}